// Round 17
// baseline (476.555 us; speedup 1.0000x reference)
//
#include <hip/hip_runtime.h>
#include <math.h>

#define BB 4
#define TT 1024
#define CC 48
#define HH 8
#define THD_B (HH*TT)     // 8192 token-heads per batch
#define FF 576            // padded feature dim (528 bilinear + qn/kn + pad), 9*64
#define CK (CC*16)        // 768

// per-batch buffer strides in ushorts
#define QF_S  ((size_t)THD_B*FF)     // 4,718,592
#define VT_S  ((size_t)THD_B*CK)     // 6,291,456
#define AO_S  ((size_t)HH*TT*768)    // 6,291,456
#define HTB_S ((size_t)16*TT*48)     // 786,432

typedef __attribute__((ext_vector_type(8))) short bf16x8;
typedef __attribute__((ext_vector_type(4))) float f32x4;

// per-component tables: grade slice, e0 slice, e0 source comp, feature index
// e0 maps move s->d: 0->1, 2->5, 3->6, 4->7, 8->11, 9->12, 10->13, 14->15
__constant__ int c_gj[16]   = {0,1,1,1,1,2,2,2,2,2,2,3,3,3,3,4};
__constant__ int c_ej[16]   = {-1,5,-1,-1,-1,6,6,6,-1,-1,-1,7,7,7,-1,8};
__constant__ int c_srcj[16] = {0,0,0,0,0,2,3,4,0,0,0,8,9,10,0,14};
__constant__ int c_fi[16]   = {0,-1,1,2,3,-1,-1,-1,4,5,6,8,9,10,7,-1};

__device__ inline ushort f2bf(float x) {           // RNE float->bf16
  union { float f; unsigned u; } a; a.f = x;
  unsigned r = a.u + 0x7FFFu + ((a.u >> 16) & 1u);
  return (ushort)(r >> 16);
}
__device__ inline float bf2f(ushort u) {
  union { unsigned u; float f; } a; a.u = ((unsigned)u) << 16; return a.f;
}
// LDS tile [rows][64 ushorts]; 16B-chunk XOR swizzle on low 2 bits (involution)
__device__ inline int swz64(int row, int chunk) {
  return row*64 + (((chunk & 4) | ((chunk ^ (row >> 2)) & 3)) << 3);
}
// async global->LDS, 16B per lane; LDS dest = wave-uniform base + lane*16 (linear).
// Swizzle realized by pre-permuting the per-lane GLOBAL source chunk (rule #21).
__device__ inline void glds16(const ushort* g, ushort* l) {
  __builtin_amdgcn_global_load_lds((const __attribute__((address_space(1))) void*)g,
                                   (__attribute__((address_space(3))) void*)l, 16, 0, 0);
}

// ---------------- sentinel fill (workspace too small diagnostic) ----------------
__global__ void kfill(float* __restrict__ p, size_t n, float v) {
  size_t i = (size_t)blockIdx.x*256 + threadIdx.x;
  size_t stride = (size_t)gridDim.x*256;
  for (; i < n; i += stride) p[i] = v;
}

// ---------------- K0b: out-proj weights, bf16, [j][o][k], k = h*96 + {g | e} ----------------
__global__ void k0b_wplanes(const float* __restrict__ w_next,
                            ushort* __restrict__ wBt) {
  int idx = blockIdx.x*256 + threadIdx.x;   // over 16*48*384
  if (idx >= 16*48*384) return;
  int j = idx / (48*384), rem = idx % (48*384), o = rem / 384, i = rem % 384;
  int h = i / 48, c = i % 48;
  int g = c_gj[j], e = c_ej[j];
  ushort* dst = wBt + ((size_t)j*48 + o)*768;
  dst[h*96 + c]      = f2bf(w_next[((size_t)o*384 + i)*9 + g]);
  dst[h*96 + 48 + c] = (e >= 0) ? f2bf(w_next[((size_t)o*384 + i)*9 + e]) : (ushort)0;
}

// ---------------- K0c: per-plane qkv weights, bf16, [j][o(1152)][96] ----------------
__global__ void k0c_wqkv(const float* __restrict__ w_attn,
                         ushort* __restrict__ wB) {
  int idx = blockIdx.x*256 + threadIdx.x;   // over 16*1152*48
  if (idx >= 16*1152*48) return;
  int j = idx / (1152*48), rem = idx % (1152*48), o = rem / 48, i = rem % 48;
  int g = c_gj[j], e = c_ej[j];
  float scl = (j >= 11 && j <= 13 && o < 768) ? 1.41421356237f : 1.0f;
  ushort* dst = wB + ((size_t)j*1152 + o)*96;
  dst[i]      = f2bf(w_attn[((size_t)o*48 + i)*9 + g] * scl);
  dst[48 + i] = (e >= 0) ? f2bf(w_attn[((size_t)o*48 + i)*9 + e] * scl) : (ushort)0;
}

// ---------------- K1: equi RMS norm -> hTb[comp][token][chan] (bf16), grid (TT, nb) ----------------
__global__ __launch_bounds__(256) void k1_rmsnorm(const float* __restrict__ hidden,
                                                  const float* __restrict__ lnw,
                                                  ushort* __restrict__ hTb0, int b0) {
  const int lb = blockIdx.y;
  const float* hidden_b = hidden + (size_t)(b0 + lb)*TT*768;
  ushort* hTb = hTb0 + (size_t)lb*HTB_S;
  int n = blockIdx.x, tid = threadIdx.x;
  __shared__ float xs[768];
  __shared__ float red[256];
  float psum = 0.f;
  for (int e = tid; e < 768; e += 256) {
    float v = hidden_b[(size_t)n*768 + e];
    xs[e] = v;
    int k = e & 15;
    if ((0x471Du >> k) & 1u) psum += v*v;   // INV = {0,2,3,4,8,9,10,14}
  }
  red[tid] = psum;
  __syncthreads();
  for (int s = 128; s > 0; s >>= 1) { if (tid < s) red[tid] += red[tid+s]; __syncthreads(); }
  float scale = rsqrtf(red[0]/48.0f + 1e-6f);
  for (int e = tid; e < 768; e += 256) {
    int k = e / 48, i = e % 48;
    hTb[((size_t)k*TT + n)*48 + i] = f2bf(xs[i*16 + k] * scale * lnw[i]);
  }
}

// ---------------- K1b: qkv equi-linear, bf16 MFMA plane-GEMMs ----------------
// grid (8 t-tiles(128), 9 o-tiles(128), nb*16); z = lb*16 + j
__global__ __launch_bounds__(256) void k1b_qkv_mfma(const ushort* __restrict__ hTb0,
                                                    const ushort* __restrict__ wB,
                                                    const float* __restrict__ b_attn,
                                                    ushort* __restrict__ qf0,
                                                    ushort* __restrict__ kf0,
                                                    ushort* __restrict__ vT0) {
  const int j = blockIdx.z & 15, lb = blockIdx.z >> 4;
  const int oy = blockIdx.y;
  const int fi = c_fi[j];
  if (fi < 0 && oy < 6) return;            // q/k never use comps {1,5,6,7,15}
  const ushort* hTb = hTb0 + (size_t)lb*HTB_S;
  ushort* qf = qf0 + (size_t)lb*QF_S;
  ushort* kf = kf0 + (size_t)lb*QF_S;
  ushort* vT = vT0 + (size_t)lb*VT_S;
  const int t0 = blockIdx.x*128, o0 = oy*128;
  const int srcj = c_srcj[j];
  __shared__ __align__(16) ushort smem[2*128*104];   // As | Bs, reused as E
  ushort* As = smem;
  ushort* Bs = smem + 128*104;
  const int tid = threadIdx.x;
  const int lane = tid & 63, wid = tid >> 6;
  const int wr = wid >> 1, wc = wid & 1;
  const int rr = lane & 15, kq = lane >> 4;
  {
    const int r = tid >> 1, half = tid & 1;
    const ushort* sa = hTb + ((size_t)(half ? srcj : j)*TT + t0 + r)*48;
    const ushort* sb = wB + ((size_t)j*1152 + o0 + r)*96 + half*48;
    #pragma unroll
    for (int i = 0; i < 6; ++i) {          // 48 ushorts = 6 x 16B chunks
      *(ulonglong2*)(&As[r*104 + half*48 + i*8]) = *(const ulonglong2*)(sa + i*8);
      *(ulonglong2*)(&Bs[r*104 + half*48 + i*8]) = *(const ulonglong2*)(sb + i*8);
    }
  }
  __syncthreads();
  f32x4 acc[4][4] = {};
  #pragma unroll
  for (int ks = 0; ks < 3; ++ks) {
    bf16x8 af[4], bfv[4];
    #pragma unroll
    for (int m = 0; m < 4; ++m)
      af[m] = *(const bf16x8*)(&As[(wr*64 + m*16 + rr)*104 + ks*32 + kq*8]);
    #pragma unroll
    for (int n = 0; n < 4; ++n)
      bfv[n] = *(const bf16x8*)(&Bs[(wc*64 + n*16 + rr)*104 + ks*32 + kq*8]);
    #pragma unroll
    for (int m = 0; m < 4; ++m)
      #pragma unroll
      for (int n = 0; n < 4; ++n)
        acc[m][n] = __builtin_amdgcn_mfma_f32_16x16x32_bf16(af[m], bfv[n], acc[m][n], 0, 0, 0);
  }
  const int cr = (lane >> 4) << 2, cc = lane & 15;
  __syncthreads();                         // all frag reads done -> reuse smem
  ushort* E = smem;                        // 128x136 ushorts
  if (oy < 6) {
    // q/k: E[t][o] (pad 136), scatter 2B writes, coalesced row reads
    #pragma unroll
    for (int n = 0; n < 4; ++n) {
      const int ol = wc*64 + n*16 + cc;
      const float bias = (j == 0) ? b_attn[o0 + ol] : 0.f;
      #pragma unroll
      for (int m = 0; m < 4; ++m) {
        const int tb = wr*64 + m*16 + cr;
        #pragma unroll
        for (int r = 0; r < 4; ++r)
          E[(tb + r)*136 + ol] = f2bf(acc[m][n][r] + bias);
      }
    }
    __syncthreads();
    #pragma unroll
    for (int i = 0; i < 8; ++i) {
      int s = tid + 256*i;
      int tl = s >> 4, o8 = (s & 15)*8;
      ulonglong2 v = *(const ulonglong2*)(&E[tl*136 + o8]);
      int og = o0 + o8;
      int qkv = og / 384, rem = og % 384, head = rem / 48, c = rem % 48;
      ushort* dst = (qkv == 0 ? qf : kf) + ((size_t)head*TT + t0 + tl)*FF + fi*48 + c;
      *(ulonglong2*)dst = v;
    }
  } else {
    // v: E[o][t] (pad 136), packed 8B writes, coalesced t-row reads -> vT direct
    #pragma unroll
    for (int n = 0; n < 4; ++n) {
      const int ol = wc*64 + n*16 + cc;
      const float bias = (j == 0) ? b_attn[o0 + ol] : 0.f;
      #pragma unroll
      for (int m = 0; m < 4; ++m) {
        const int tb = wr*64 + m*16 + cr;
        uint2 pk;
        pk.x = (uint)f2bf(acc[m][n][0] + bias) | ((uint)f2bf(acc[m][n][1] + bias) << 16);
        pk.y = (uint)f2bf(acc[m][n][2] + bias) | ((uint)f2bf(acc[m][n][3] + bias) << 16);
        *(uint2*)(&E[ol*136 + tb]) = pk;
      }
    }
    __syncthreads();
    #pragma unroll
    for (int i = 0; i < 8; ++i) {
      int s = tid + 256*i;
      int ol = s >> 4, t8 = (s & 15)*8;
      ulonglong2 v = *(const ulonglong2*)(&E[ol*136 + t8]);
      int og = o0 + ol;
      int rem = og % 384, head = rem / 48, c = rem % 48;
      ushort* dst = vT + ((size_t)((head*16 + j)*48 + c))*TT + t0 + t8;
      *(ulonglong2*)dst = v;
    }
  }
}

// ---------------- K1c: qn/kn rank-1 features, one wave per token-head; grid (THD_B/4, nb) ----------------
__global__ __launch_bounds__(256) void k1c_extras(ushort* __restrict__ qf0,
                                                  ushort* __restrict__ kf0) {
  const int lb = blockIdx.y;
  int th = blockIdx.x*4 + (threadIdx.x >> 6);
  int lane = threadIdx.x & 63;
  ushort* q = qf0 + (size_t)lb*QF_S + (size_t)th*FF;
  ushort* k = kf0 + (size_t)lb*QF_S + (size_t)th*FF;
  float qn = 0.f, kn = 0.f;
  if (lane < 36) {                       // elements 384..527 (sqrt2*proj planes)
    ushort4 a = *(const ushort4*)(q + 384 + lane*4);
    ushort4 b = *(const ushort4*)(k + 384 + lane*4);
    float x;
    x = bf2f(a.x); qn += x*x;  x = bf2f(a.y); qn += x*x;
    x = bf2f(a.z); qn += x*x;  x = bf2f(a.w); qn += x*x;
    x = bf2f(b.x); kn += x*x;  x = bf2f(b.y); kn += x*x;
    x = bf2f(b.z); kn += x*x;  x = bf2f(b.w); kn += x*x;
  }
  #pragma unroll
  for (int off = 32; off; off >>= 1) {
    qn += __shfl_xor(qn, off, 64);
    kn += __shfl_xor(kn, off, 64);
  }
  if (lane == 0) {                       // features hold sqrt(2)*proj -> *0.5
    q[528] = f2bf(qn*0.5f); q[529] = 0x3F80u;      // 1.0
    k[528] = 0xBF80u;       k[529] = f2bf(-kn*0.5f);
  }
  if (lane < 46) { q[530+lane] = 0; k[530+lane] = 0; }  // zero pad to FF=576
}

// ---------------- K2f: fused attention per (t-tile 64, head, batch) ----------------
// U = exp(q.k/sqrt(384)) kept entirely in LDS (64x1024 bf16 = 128KB), then PV from LDS.
// Kills the 67MB U HBM round-trip + 309MB re-reads; working set now fits L3.
// 512 threads = 8 waves: wave w -> t-rows (w&3)*16.., col-half (w>>2)*64.
__global__ __launch_bounds__(512) void k2f_attn(const ushort* __restrict__ qf0,
                                                const ushort* __restrict__ kf0,
                                                const ushort* __restrict__ vT0,
                                                ushort* __restrict__ aoH0) {
  const int h = blockIdx.y, lb = blockIdx.z;
  const int t0 = blockIdx.x*64;
  const ushort* Qg = qf0 + (size_t)lb*QF_S + (size_t)h*TT*FF;
  const ushort* Kg = kf0 + (size_t)lb*QF_S + (size_t)h*TT*FF;
  const ushort* Vg = vT0 + (size_t)lb*VT_S + (size_t)h*CK*TT;
  ushort* aoH = aoH0 + (size_t)lb*AO_S;

  // U[64*1024] | As[64*64] | Bs[128*64] | part[2][64]f32 | invs[64]f32  = 156.4KB
  __shared__ __align__(16) ushort smem[65536 + 4096 + 8192 + 384];
  ushort* U  = smem;
  ushort* As = smem + 65536;
  ushort* Bs = smem + 65536 + 4096;
  float*  part = (float*)(smem + 65536 + 4096 + 8192);   // [2][64]
  float*  invs = part + 128;                              // [64]

  const int tid = threadIdx.x;
  const int lane = tid & 63, w = tid >> 6;         // 8 waves
  const int tb = (w & 3)*16, sh = (w >> 2)*64;     // wave tile: 16t x 64col
  const int rr = lane & 15, kq = lane >> 4;
  const int cr = (lane >> 4) << 2, cc = lane & 15;
  const int lr8 = lane >> 3, ch = lane & 7;
  const float iscl = 0.051031036307982884f;        // 1/sqrt(384)

  float partial[4] = {0.f, 0.f, 0.f, 0.f};

  // ---- QK phase: 8 s-chunks of 128, K = FF loop ----
  for (int s0 = 0; s0 < TT; s0 += 128) {
    f32x4 acc[4] = {};
    for (int kk = 0; kk < FF; kk += 64) {
      __syncthreads();
      {                                            // A: q 64 rows, wave w -> rows w*8+lr8
        int r = w*8 + lr8;
        int sch = (ch & 4) | ((ch ^ (r >> 2)) & 3);
        glds16(Qg + (size_t)(t0 + r)*FF + kk + sch*8, &As[w*8*64]);
      }
      #pragma unroll
      for (int i = 0; i < 2; ++i) {                // B: k 128 rows
        int r = i*64 + w*8 + lr8;
        int sch = (ch & 4) | ((ch ^ (r >> 2)) & 3);
        glds16(Kg + (size_t)(s0 + r)*FF + kk + sch*8, &Bs[(i*64 + w*8)*64]);
      }
      __syncthreads();                             // drains vmcnt -> LDS valid
      #pragma unroll
      for (int ks = 0; ks < 2; ++ks) {
        bf16x8 af = *(const bf16x8*)(&As[swz64(tb + rr, ks*4 + kq)]);
        #pragma unroll
        for (int n = 0; n < 4; ++n) {
          bf16x8 bv = *(const bf16x8*)(&Bs[swz64(sh + n*16 + rr, ks*4 + kq)]);
          acc[n] = __builtin_amdgcn_mfma_f32_16x16x32_bf16(af, bv, acc[n], 0, 0, 0);
        }
      }
    }
    // epilogue: exp (bounded logits, no max-sub) -> U LDS (swizzled) + row partials
    #pragma unroll
    for (int n = 0; n < 4; ++n)
      #pragma unroll
      for (int j = 0; j < 4; ++j) {
        int row = tb + cr + j;
        int col = s0 + sh + n*16 + cc;
        ushort u = f2bf(__expf(acc[n][j]*iscl));
        int kb = col >> 6, chk = (col >> 3) & 7, el = col & 7;
        int szc = (chk & 4) | ((chk ^ (row >> 2)) & 3);
        U[row*1024 + kb*64 + szc*8 + el] = u;
        partial[j] += bf2f(u);
      }
  }
  // row sums: 16 lanes (cc) share each row
  #pragma unroll
  for (int j = 0; j < 4; ++j)
    #pragma unroll
    for (int off = 1; off < 16; off <<= 1)
      partial[j] += __shfl_xor(partial[j], off, 64);
  if (cc == 0) {
    #pragma unroll
    for (int j = 0; j < 4; ++j)
      part[(w >> 2)*64 + tb + cr + j] = partial[j];
  }
  __syncthreads();
  if (tid < 64) invs[tid] = 1.0f / (part[tid] + part[64 + tid]);

  // ---- PV phase: 6 c-chunks of 128, K = TT loop, A-frags straight from U LDS ----
  for (int c0 = 0; c0 < CK; c0 += 128) {
    f32x4 acc[4] = {};
    for (int kk = 0; kk < TT; kk += 64) {
      __syncthreads();                             // protects Bs/E from prior phase
      #pragma unroll
      for (int i = 0; i < 2; ++i) {                // B: vT 128 rows (c-dim)
        int r = i*64 + w*8 + lr8;
        int sch = (ch & 4) | ((ch ^ (r >> 2)) & 3);
        glds16(Vg + (size_t)(c0 + r)*TT + kk + sch*8, &Bs[(i*64 + w*8)*64]);
      }
      __syncthreads();
      const int kb = kk >> 6;
      #pragma unroll
      for (int ks = 0; ks < 2; ++ks) {
        const int rowa = tb + rr, chnk = ks*4 + kq;
        const int szc = (chnk & 4) | ((chnk ^ (rowa >> 2)) & 3);
        bf16x8 af = *(const bf16x8*)(&U[rowa*1024 + kb*64 + szc*8]);
        #pragma unroll
        for (int n = 0; n < 4; ++n) {
          bf16x8 bv = *(const bf16x8*)(&Bs[swz64(sh + n*16 + rr, chnk)]);
          acc[n] = __builtin_amdgcn_mfma_f32_16x16x32_bf16(af, bv, acc[n], 0, 0, 0);
        }
      }
    }
    __syncthreads();                               // Bs reads done -> reuse As|Bs as E
    ushort* E = As;                                // needs 64*136 = 8704 <= 12288
    #pragma unroll
    for (int n = 0; n < 4; ++n)
      #pragma unroll
      for (int j = 0; j < 4; ++j) {
        int row = tb + cr + j;
        int cl = sh + n*16 + cc;
        E[row*136 + cl] = f2bf(acc[n][j] * invs[row]);
      }
    __syncthreads();
    #pragma unroll
    for (int i = 0; i < 2; ++i) {                  // coalesced 16B stores
      int s = tid + 512*i;
      int tl = s >> 4, c8 = (s & 15)*8;
      ulonglong2 v = *(const ulonglong2*)(&E[tl*136 + c8]);
      *(ulonglong2*)(aoH + ((size_t)h*TT + t0 + tl)*768 + c0 + c8) = v;
    }
  }
}

// ---------------- K3: out-proj as 16 plane-GEMMs over head-major aoH ----------------
// grid (16 t-tiles(64), 16 j, nb); K = 8 head-chunks x 96 ([ao_j(h) | ao_srcj(h)])
__global__ __launch_bounds__(256) void k3_mfma(const ushort* __restrict__ aoH0,
                                               const ushort* __restrict__ wBt,
                                               const float* __restrict__ b_next,
                                               const float* __restrict__ hidden,
                                               float* __restrict__ out, int b0) {
  const int lb = blockIdx.z;
  const ushort* aoH = aoH0 + (size_t)lb*AO_S;
  const float* hidden_b = hidden + (size_t)(b0 + lb)*TT*768;
  float* out_b = out + (size_t)(b0 + lb)*TT*768;
  const int j = blockIdx.y, t0 = blockIdx.x*64;
  const int srcj = c_srcj[j];
  __shared__ __align__(16) ushort As[64*104];
  __shared__ __align__(16) ushort Bs[48*104];
  const int tid = threadIdx.x;
  const int lane = tid & 63, wid = tid >> 6;
  const int rr = lane & 15, kq = lane >> 4;
  const ushort* bw = wBt + (size_t)j*48*768;
  const int ar = tid >> 2, aq = tid & 3;       // stage: 4 thr/row, 3 chunks each
  f32x4 acc[3] = {};
  for (int hh = 0; hh < HH; ++hh) {
    __syncthreads();
    {
      const ushort* rowp = aoH + ((size_t)hh*TT + t0 + ar)*768;
      #pragma unroll
      for (int q = 0; q < 3; ++q) {
        int ci = aq*3 + q;                     // 0..11
        const ushort* src = rowp + ((ci < 6) ? (j*48 + ci*8) : (srcj*48 + (ci - 6)*8));
        *(ulonglong2*)(&As[ar*104 + ci*8]) = *(const ulonglong2*)src;
      }
      if (tid < 192) {
        const ushort* brow = bw + (size_t)ar*768 + hh*96;
        #pragma unroll
        for (int q = 0; q < 3; ++q) {
          int ci = aq*3 + q;
          *(ulonglong2*)(&Bs[ar*104 + ci*8]) = *(const ulonglong2*)(brow + ci*8);
        }
      }
    }
    __syncthreads();
    #pragma unroll
    for (int ks = 0; ks < 3; ++ks) {
      bf16x8 af = *(const bf16x8*)(&As[(wid*16 + rr)*104 + ks*32 + kq*8]);
      #pragma unroll
      for (int n = 0; n < 3; ++n) {
        bf16x8 bf = *(const bf16x8*)(&Bs[(n*16 + rr)*104 + ks*32 + kq*8]);
        acc[n] = __builtin_amdgcn_mfma_f32_16x16x32_bf16(af, bf, acc[n], 0, 0, 0);
      }
    }
  }
  const int cr = (lane >> 4) << 2, cc = lane & 15;
  #pragma unroll
  for (int n = 0; n < 3; ++n) {
    int o = n*16 + cc;
    float bb = (j == 0) ? b_next[o] : 0.f;
    #pragma unroll
    for (int r = 0; r < 4; ++r) {
      int t = t0 + wid*16 + cr + r;
      size_t off = (size_t)t*768 + o*16 + j;
      out_b[off] = acc[n][r] + bb + hidden_b[off];
    }
  }
}

extern "C" void kernel_launch(void* const* d_in, const int* in_sizes, int n_in,
                              void* d_out, int out_size, void* d_ws, size_t ws_size,
                              hipStream_t stream) {
  const float* hidden = (const float*)d_in[0];
  const float* w_attn = (const float*)d_in[1];
  const float* b_attn = (const float*)d_in[2];
  const float* w_next = (const float*)d_in[3];
  const float* b_next = (const float*)d_in[4];
  const float* ln_w   = (const float*)d_in[5];
  float* out = (float*)d_out;
  float* ws = (float*)d_ws;

  // per-batch floats: (qf+kf) + vT/2 + aoH/2 + hTb/2 = 11,403,264
  const size_t PER_B_FL = QF_S + VT_S/2 + AO_S/2 + HTB_S/2;
  const size_t W_FL = (16*48*768 + 16*1152*96)/2;   // wBt + wB = 589,824 floats
  int nb = 0;
  for (int g = 4; g >= 1; g >>= 1)
    if (ws_size >= ((size_t)g*PER_B_FL + W_FL)*4) { nb = g; break; }
  if (nb == 0) {
    kfill<<<2048, 256, 0, stream>>>(out, (size_t)out_size, 1.0e6f);
    return;
  }

  ushort* qf  = (ushort*)ws;                       // nb * QF_S
  ushort* kf  = qf + (size_t)nb*QF_S;              // nb * QF_S
  ushort* vT  = kf + (size_t)nb*QF_S;              // nb * VT_S
  ushort* aoH = vT + (size_t)nb*VT_S;              // nb * AO_S
  ushort* hTb = aoH + (size_t)nb*AO_S;             // nb * HTB_S
  ushort* wBt = hTb + (size_t)nb*HTB_S;            // 16*48*768
  ushort* wB  = wBt + (size_t)16*48*768;           // 16*1152*96

  k0b_wplanes<<<1152, 256, 0, stream>>>(w_next, wBt);
  k0c_wqkv<<<3456, 256, 0, stream>>>(w_attn, wB);
  for (int b0 = 0; b0 < BB; b0 += nb) {
    k1_rmsnorm<<<dim3(TT, nb), 256, 0, stream>>>(hidden, ln_w, hTb, b0);
    k1b_qkv_mfma<<<dim3(8, 9, 16*nb), 256, 0, stream>>>(hTb, wB, b_attn, qf, kf, vT);
    k1c_extras<<<dim3(THD_B/4, nb), 256, 0, stream>>>(qf, kf);
    k2f_attn<<<dim3(16, HH, nb), 512, 0, stream>>>(qf, kf, vT, aoH);
    k3_mfma<<<dim3(16, 16, nb), 256, 0, stream>>>(aoH, wBt, b_next, hidden, out, b0);
  }
}

// Round 18
// 303.559 us; speedup vs baseline: 1.5699x; 1.5699x over previous
//
#include <hip/hip_runtime.h>
#include <math.h>

#define BB 4
#define TT 1024
#define CC 48
#define HH 8
#define THD_B (HH*TT)     // 8192 token-heads per batch
#define FF 576            // padded feature dim (528 bilinear + qn/kn + pad), 9*64
#define CK (CC*16)        // 768

// per-batch buffer strides in ushorts (f32 for rowpart)
#define QF_S  ((size_t)THD_B*FF)     // 4,718,592
#define VT_S  ((size_t)THD_B*CK)     // 6,291,456
#define AO_S  ((size_t)HH*TT*768)    // 6,291,456
#define U_S   ((size_t)HH*TT*TT)     // 8,388,608
#define RP_S  ((size_t)HH*8*TT)      // 65,536 f32
#define HTB_S ((size_t)16*TT*48)     // 786,432

typedef __attribute__((ext_vector_type(8))) short bf16x8;
typedef __attribute__((ext_vector_type(4))) float f32x4;

// per-component tables: grade slice, e0 slice, e0 source comp, feature index
// e0 maps move s->d: 0->1, 2->5, 3->6, 4->7, 8->11, 9->12, 10->13, 14->15
__constant__ int c_gj[16]   = {0,1,1,1,1,2,2,2,2,2,2,3,3,3,3,4};
__constant__ int c_ej[16]   = {-1,5,-1,-1,-1,6,6,6,-1,-1,-1,7,7,7,-1,8};
__constant__ int c_srcj[16] = {0,0,0,0,0,2,3,4,0,0,0,8,9,10,0,14};
__constant__ int c_fi[16]   = {0,-1,1,2,3,-1,-1,-1,4,5,6,8,9,10,7,-1};

__device__ inline ushort f2bf(float x) {           // RNE float->bf16
  union { float f; unsigned u; } a; a.f = x;
  unsigned r = a.u + 0x7FFFu + ((a.u >> 16) & 1u);
  return (ushort)(r >> 16);
}
__device__ inline float bf2f(ushort u) {
  union { unsigned u; float f; } a; a.u = ((unsigned)u) << 16; return a.f;
}
// LDS tile [rows][64 ushorts]; 16B-chunk XOR swizzle on low 2 bits (involution)
__device__ inline int swz64(int row, int chunk) {
  return row*64 + (((chunk & 4) | ((chunk ^ (row >> 2)) & 3)) << 3);
}
// async global->LDS, 16B per lane; LDS dest = uniform base + lane*16 (linear).
// Swizzle realized by pre-permuting the per-lane GLOBAL source chunk (rule #21).
__device__ inline void glds16(const ushort* g, ushort* l) {
  __builtin_amdgcn_global_load_lds((const __attribute__((address_space(1))) void*)g,
                                   (__attribute__((address_space(3))) void*)l, 16, 0, 0);
}

// ---------------- sentinel fill (workspace too small diagnostic) ----------------
__global__ void kfill(float* __restrict__ p, size_t n, float v) {
  size_t i = (size_t)blockIdx.x*256 + threadIdx.x;
  size_t stride = (size_t)gridDim.x*256;
  for (; i < n; i += stride) p[i] = v;
}

// ---------------- K0b: out-proj weights, bf16, [j][o][k], k = h*96 + {g | e} ----------------
__global__ void k0b_wplanes(const float* __restrict__ w_next,
                            ushort* __restrict__ wBt) {
  int idx = blockIdx.x*256 + threadIdx.x;   // over 16*48*384
  if (idx >= 16*48*384) return;
  int j = idx / (48*384), rem = idx % (48*384), o = rem / 384, i = rem % 384;
  int h = i / 48, c = i % 48;
  int g = c_gj[j], e = c_ej[j];
  ushort* dst = wBt + ((size_t)j*48 + o)*768;
  dst[h*96 + c]      = f2bf(w_next[((size_t)o*384 + i)*9 + g]);
  dst[h*96 + 48 + c] = (e >= 0) ? f2bf(w_next[((size_t)o*384 + i)*9 + e]) : (ushort)0;
}

// ---------------- K0c: per-plane qkv weights, bf16, [j][o(1152)][96] ----------------
__global__ void k0c_wqkv(const float* __restrict__ w_attn,
                         ushort* __restrict__ wB) {
  int idx = blockIdx.x*256 + threadIdx.x;   // over 16*1152*48
  if (idx >= 16*1152*48) return;
  int j = idx / (1152*48), rem = idx % (1152*48), o = rem / 48, i = rem % 48;
  int g = c_gj[j], e = c_ej[j];
  float scl = (j >= 11 && j <= 13 && o < 768) ? 1.41421356237f : 1.0f;
  ushort* dst = wB + ((size_t)j*1152 + o)*96;
  dst[i]      = f2bf(w_attn[((size_t)o*48 + i)*9 + g] * scl);
  dst[48 + i] = (e >= 0) ? f2bf(w_attn[((size_t)o*48 + i)*9 + e] * scl) : (ushort)0;
}

// ---------------- K1: equi RMS norm -> hTb[comp][token][chan] (bf16), grid (TT, nb) ----------------
__global__ __launch_bounds__(256) void k1_rmsnorm(const float* __restrict__ hidden,
                                                  const float* __restrict__ lnw,
                                                  ushort* __restrict__ hTb0, int b0) {
  const int lb = blockIdx.y;
  const float* hidden_b = hidden + (size_t)(b0 + lb)*TT*768;
  ushort* hTb = hTb0 + (size_t)lb*HTB_S;
  int n = blockIdx.x, tid = threadIdx.x;
  __shared__ float xs[768];
  __shared__ float red[256];
  float psum = 0.f;
  for (int e = tid; e < 768; e += 256) {
    float v = hidden_b[(size_t)n*768 + e];
    xs[e] = v;
    int k = e & 15;
    if ((0x471Du >> k) & 1u) psum += v*v;   // INV = {0,2,3,4,8,9,10,14}
  }
  red[tid] = psum;
  __syncthreads();
  for (int s = 128; s > 0; s >>= 1) { if (tid < s) red[tid] += red[tid+s]; __syncthreads(); }
  float scale = rsqrtf(red[0]/48.0f + 1e-6f);
  for (int e = tid; e < 768; e += 256) {
    int k = e / 48, i = e % 48;
    hTb[((size_t)k*TT + n)*48 + i] = f2bf(xs[i*16 + k] * scale * lnw[i]);
  }
}

// ---------------- K1b: qkv equi-linear, bf16 MFMA plane-GEMMs ----------------
// grid (8 t-tiles(128), 9 o-tiles(128), nb*16); z = lb*16 + j
__global__ __launch_bounds__(256) void k1b_qkv_mfma(const ushort* __restrict__ hTb0,
                                                    const ushort* __restrict__ wB,
                                                    const float* __restrict__ b_attn,
                                                    ushort* __restrict__ qf0,
                                                    ushort* __restrict__ kf0,
                                                    ushort* __restrict__ vT0) {
  const int j = blockIdx.z & 15, lb = blockIdx.z >> 4;
  const int oy = blockIdx.y;
  const int fi = c_fi[j];
  if (fi < 0 && oy < 6) return;            // q/k never use comps {1,5,6,7,15}
  const ushort* hTb = hTb0 + (size_t)lb*HTB_S;
  ushort* qf = qf0 + (size_t)lb*QF_S;
  ushort* kf = kf0 + (size_t)lb*QF_S;
  ushort* vT = vT0 + (size_t)lb*VT_S;
  const int t0 = blockIdx.x*128, o0 = oy*128;
  const int srcj = c_srcj[j];
  __shared__ __align__(16) ushort smem[2*128*104];   // As | Bs, reused as E
  ushort* As = smem;
  ushort* Bs = smem + 128*104;
  const int tid = threadIdx.x;
  const int lane = tid & 63, wid = tid >> 6;
  const int wr = wid >> 1, wc = wid & 1;
  const int rr = lane & 15, kq = lane >> 4;
  {
    const int r = tid >> 1, half = tid & 1;
    const ushort* sa = hTb + ((size_t)(half ? srcj : j)*TT + t0 + r)*48;
    const ushort* sb = wB + ((size_t)j*1152 + o0 + r)*96 + half*48;
    #pragma unroll
    for (int i = 0; i < 6; ++i) {          // 48 ushorts = 6 x 16B chunks
      *(ulonglong2*)(&As[r*104 + half*48 + i*8]) = *(const ulonglong2*)(sa + i*8);
      *(ulonglong2*)(&Bs[r*104 + half*48 + i*8]) = *(const ulonglong2*)(sb + i*8);
    }
  }
  __syncthreads();
  f32x4 acc[4][4] = {};
  #pragma unroll
  for (int ks = 0; ks < 3; ++ks) {
    bf16x8 af[4], bfv[4];
    #pragma unroll
    for (int m = 0; m < 4; ++m)
      af[m] = *(const bf16x8*)(&As[(wr*64 + m*16 + rr)*104 + ks*32 + kq*8]);
    #pragma unroll
    for (int n = 0; n < 4; ++n)
      bfv[n] = *(const bf16x8*)(&Bs[(wc*64 + n*16 + rr)*104 + ks*32 + kq*8]);
    #pragma unroll
    for (int m = 0; m < 4; ++m)
      #pragma unroll
      for (int n = 0; n < 4; ++n)
        acc[m][n] = __builtin_amdgcn_mfma_f32_16x16x32_bf16(af[m], bfv[n], acc[m][n], 0, 0, 0);
  }
  const int cr = (lane >> 4) << 2, cc = lane & 15;
  __syncthreads();                         // all frag reads done -> reuse smem
  ushort* E = smem;                        // 128x136 ushorts
  if (oy < 6) {
    // q/k: E[t][o] (pad 136), scatter 2B writes, coalesced row reads
    #pragma unroll
    for (int n = 0; n < 4; ++n) {
      const int ol = wc*64 + n*16 + cc;
      const float bias = (j == 0) ? b_attn[o0 + ol] : 0.f;
      #pragma unroll
      for (int m = 0; m < 4; ++m) {
        const int tb = wr*64 + m*16 + cr;
        #pragma unroll
        for (int r = 0; r < 4; ++r)
          E[(tb + r)*136 + ol] = f2bf(acc[m][n][r] + bias);
      }
    }
    __syncthreads();
    #pragma unroll
    for (int i = 0; i < 8; ++i) {
      int s = tid + 256*i;
      int tl = s >> 4, o8 = (s & 15)*8;
      ulonglong2 v = *(const ulonglong2*)(&E[tl*136 + o8]);
      int og = o0 + o8;
      int qkv = og / 384, rem = og % 384, head = rem / 48, c = rem % 48;
      ushort* dst = (qkv == 0 ? qf : kf) + ((size_t)head*TT + t0 + tl)*FF + fi*48 + c;
      *(ulonglong2*)dst = v;
    }
  } else {
    // v: E[o][t] (pad 136), packed 8B writes, coalesced t-row reads -> vT direct
    #pragma unroll
    for (int n = 0; n < 4; ++n) {
      const int ol = wc*64 + n*16 + cc;
      const float bias = (j == 0) ? b_attn[o0 + ol] : 0.f;
      #pragma unroll
      for (int m = 0; m < 4; ++m) {
        const int tb = wr*64 + m*16 + cr;
        uint2 pk;
        pk.x = (uint)f2bf(acc[m][n][0] + bias) | ((uint)f2bf(acc[m][n][1] + bias) << 16);
        pk.y = (uint)f2bf(acc[m][n][2] + bias) | ((uint)f2bf(acc[m][n][3] + bias) << 16);
        *(uint2*)(&E[ol*136 + tb]) = pk;
      }
    }
    __syncthreads();
    #pragma unroll
    for (int i = 0; i < 8; ++i) {
      int s = tid + 256*i;
      int ol = s >> 4, t8 = (s & 15)*8;
      ulonglong2 v = *(const ulonglong2*)(&E[ol*136 + t8]);
      int og = o0 + ol;
      int rem = og % 384, head = rem / 48, c = rem % 48;
      ushort* dst = vT + ((size_t)((head*16 + j)*48 + c))*TT + t0 + t8;
      *(ulonglong2*)dst = v;
    }
  }
}

// ---------------- K1c: qn/kn rank-1 features, one wave per token-head; grid (THD_B/4, nb) ----------------
__global__ __launch_bounds__(256) void k1c_extras(ushort* __restrict__ qf0,
                                                  ushort* __restrict__ kf0) {
  const int lb = blockIdx.y;
  int th = blockIdx.x*4 + (threadIdx.x >> 6);
  int lane = threadIdx.x & 63;
  ushort* q = qf0 + (size_t)lb*QF_S + (size_t)th*FF;
  ushort* k = kf0 + (size_t)lb*QF_S + (size_t)th*FF;
  float qn = 0.f, kn = 0.f;
  if (lane < 36) {                       // elements 384..527 (sqrt2*proj planes)
    ushort4 a = *(const ushort4*)(q + 384 + lane*4);
    ushort4 b = *(const ushort4*)(k + 384 + lane*4);
    float x;
    x = bf2f(a.x); qn += x*x;  x = bf2f(a.y); qn += x*x;
    x = bf2f(a.z); qn += x*x;  x = bf2f(a.w); qn += x*x;
    x = bf2f(b.x); kn += x*x;  x = bf2f(b.y); kn += x*x;
    x = bf2f(b.z); kn += x*x;  x = bf2f(b.w); kn += x*x;
  }
  #pragma unroll
  for (int off = 32; off; off >>= 1) {
    qn += __shfl_xor(qn, off, 64);
    kn += __shfl_xor(kn, off, 64);
  }
  if (lane == 0) {                       // features hold sqrt(2)*proj -> *0.5
    q[528] = f2bf(qn*0.5f); q[529] = 0x3F80u;      // 1.0
    k[528] = 0xBF80u;       k[529] = f2bf(-kn*0.5f);
  }
  if (lane < 46) { q[530+lane] = 0; k[530+lane] = 0; }  // zero pad to FF=576
}

// ---------------- K2b: U = exp((qf.kf)/sqrt(384)) bf16 + per-tile row sums ----------------
// grid (8 s-tiles(128), 16 t-tiles(64), nb*8); z = lb*8 + h. Bounded logits -> no max-sub.
__global__ __launch_bounds__(256) void k2b_logits_mfma(const ushort* __restrict__ qf0,
                                                       const ushort* __restrict__ kf0,
                                                       ushort* __restrict__ ubuf0,
                                                       float* __restrict__ rowpart0) {
  const int h = blockIdx.z & 7, lb = blockIdx.z >> 3;
  const int t0 = blockIdx.y*64, s0 = blockIdx.x*128;
  const ushort* Ag = qf0 + (size_t)lb*QF_S + (size_t)h*TT*FF;
  const ushort* Bg = kf0 + (size_t)lb*QF_S + (size_t)h*TT*FF;
  ushort* ubuf = ubuf0 + (size_t)lb*U_S;
  float* rowpart = rowpart0 + (size_t)lb*RP_S;
  __shared__ __align__(16) ushort smem[64*64 + 128*64];   // As | Bs (24KB); E reuse 64*136
  ushort* As = smem;
  ushort* Bs = smem + 64*64;
  const int tid = threadIdx.x;
  const int lane = tid & 63, wid = tid >> 6;
  const int wr = wid >> 1, wc = wid & 1;           // wave = 32t x 64s
  const int rr = lane & 15, kq = lane >> 4;
  const int lr8 = lane >> 3, ch = lane & 7;        // staging lane -> row/chunk
  f32x4 acc[2][4] = {};
  for (int kk = 0; kk < FF; kk += 64) {
    __syncthreads();
    #pragma unroll
    for (int i = 0; i < 2; ++i) {                  // A: 64 rows, 16/wave
      int r = wid*16 + i*8 + lr8;
      int sch = (ch & 4) | ((ch ^ (r >> 2)) & 3);
      glds16(Ag + (size_t)(t0 + r)*FF + kk + sch*8, &As[(wid*16 + i*8)*64]);
    }
    #pragma unroll
    for (int i = 0; i < 4; ++i) {                  // B: 128 rows, 32/wave
      int r = wid*32 + i*8 + lr8;
      int sch = (ch & 4) | ((ch ^ (r >> 2)) & 3);
      glds16(Bg + (size_t)(s0 + r)*FF + kk + sch*8, &Bs[(wid*32 + i*8)*64]);
    }
    __syncthreads();                               // drains vmcnt -> LDS valid
    #pragma unroll
    for (int ks = 0; ks < 2; ++ks) {
      bf16x8 af[2], bfv[4];
      #pragma unroll
      for (int m = 0; m < 2; ++m) af[m]  = *(const bf16x8*)(&As[swz64(wr*32 + m*16 + rr, ks*4 + kq)]);
      #pragma unroll
      for (int n = 0; n < 4; ++n) bfv[n] = *(const bf16x8*)(&Bs[swz64(wc*64 + n*16 + rr, ks*4 + kq)]);
      #pragma unroll
      for (int m = 0; m < 2; ++m)
        #pragma unroll
        for (int n = 0; n < 4; ++n)
          acc[m][n] = __builtin_amdgcn_mfma_f32_16x16x32_bf16(af[m], bfv[n], acc[m][n], 0, 0, 0);
    }
  }
  const float iscl = 0.051031036307982884f;   // 1/sqrt(384)
  const int cr = (lane >> 4) << 2, cc = lane & 15;
  __syncthreads();
  ushort* E = smem;                           // [64][136] = 8704 ushorts
  float* part = (float*)(smem + 8704);        // 256 f32 (disjoint from E)
  #pragma unroll
  for (int m = 0; m < 2; ++m)
    #pragma unroll
    for (int n = 0; n < 4; ++n) {
      const int tb = wr*32 + m*16 + cr;
      const int sl = wc*64 + n*16 + cc;
      #pragma unroll
      for (int r = 0; r < 4; ++r)
        E[(tb + r)*136 + sl] = f2bf(__expf(acc[m][n][r]*iscl));
    }
  __syncthreads();
  {                                           // per-row segment sums (row = tid>>2)
    const int row = tid >> 2, q4 = tid & 3;
    const ushort* er = &E[row*136 + q4*32];
    float seg = 0.f;
    #pragma unroll
    for (int i = 0; i < 4; ++i) {
      ulonglong2 v = *(const ulonglong2*)(er + i*8);
      const ushort* u = (const ushort*)&v;
      #pragma unroll
      for (int jj = 0; jj < 8; ++jj) seg += bf2f(u[jj]);
    }
    part[tid] = seg;
  }
  #pragma unroll
  for (int i = 0; i < 4; ++i) {               // stream U out
    int s = tid + 256*i;
    int tl = s >> 4, s8 = (s & 15)*8;
    ulonglong2 v = *(const ulonglong2*)(&E[tl*136 + s8]);
    *(ulonglong2*)(ubuf + ((size_t)h*TT + t0 + tl)*TT + s0 + s8) = v;
  }
  __syncthreads();
  if (tid < 64)
    rowpart[((size_t)h*8 + blockIdx.x)*TT + t0 + tid] =
        part[tid*4] + part[tid*4+1] + part[tid*4+2] + part[tid*4+3];
}

// ---------------- K2d: aoH[h][t][cg] = (U @ V) / rowsum, bf16 MFMA, BK=64 ----------------
// grid (6 c-tiles(128), 16 t-tiles(64), nb*8); z = lb*8 + h.
__global__ __launch_bounds__(256) void k2d_pv_mfma(const ushort* __restrict__ ubuf0,
                                                   const ushort* __restrict__ vT0,
                                                   const float* __restrict__ rowpart0,
                                                   ushort* __restrict__ aoH0) {
  const int h = blockIdx.z & 7, lb = blockIdx.z >> 3;
  const int t0 = blockIdx.y*64, c0 = blockIdx.x*128;
  const ushort* Ag = ubuf0 + (size_t)lb*U_S + (size_t)h*TT*TT;
  const ushort* Bg = vT0 + (size_t)lb*VT_S + (size_t)h*CK*TT;
  const float* rowpart = rowpart0 + (size_t)lb*RP_S;
  ushort* aoH = aoH0 + (size_t)lb*AO_S;
  __shared__ __align__(16) ushort smem[64*64 + 128*64];   // As | Bs (24KB); E reuse 64*136
  ushort* As = smem;
  ushort* Bs = smem + 64*64;
  const int tid = threadIdx.x;
  const int lane = tid & 63, wid = tid >> 6;
  const int wr = wid >> 1, wc = wid & 1;           // wave = 32t x 64c
  const int rr = lane & 15, kq = lane >> 4;
  const int lr8 = lane >> 3, ch = lane & 7;
  f32x4 acc[2][4] = {};
  for (int kk = 0; kk < TT; kk += 64) {
    __syncthreads();
    #pragma unroll
    for (int i = 0; i < 2; ++i) {                  // A: 64 rows, 16/wave
      int r = wid*16 + i*8 + lr8;
      int sch = (ch & 4) | ((ch ^ (r >> 2)) & 3);
      glds16(Ag + (size_t)(t0 + r)*TT + kk + sch*8, &As[(wid*16 + i*8)*64]);
    }
    #pragma unroll
    for (int i = 0; i < 4; ++i) {                  // B: 128 rows, 32/wave
      int r = wid*32 + i*8 + lr8;
      int sch = (ch & 4) | ((ch ^ (r >> 2)) & 3);
      glds16(Bg + (size_t)(c0 + r)*TT + kk + sch*8, &Bs[(wid*32 + i*8)*64]);
    }
    __syncthreads();                               // drains vmcnt -> LDS valid
    #pragma unroll
    for (int ks = 0; ks < 2; ++ks) {
      bf16x8 af[2], bfv[4];
      #pragma unroll
      for (int m = 0; m < 2; ++m) af[m]  = *(const bf16x8*)(&As[swz64(wr*32 + m*16 + rr, ks*4 + kq)]);
      #pragma unroll
      for (int n = 0; n < 4; ++n) bfv[n] = *(const bf16x8*)(&Bs[swz64(wc*64 + n*16 + rr, ks*4 + kq)]);
      #pragma unroll
      for (int m = 0; m < 2; ++m)
        #pragma unroll
        for (int n = 0; n < 4; ++n)
          acc[m][n] = __builtin_amdgcn_mfma_f32_16x16x32_bf16(af[m], bfv[n], acc[m][n], 0, 0, 0);
    }
  }
  const int cr = (lane >> 4) << 2, cc = lane & 15;
  __syncthreads();
  ushort* E = smem;                       // [64][136]
  float* invs = (float*)(smem + 8704);    // 64 f32 (disjoint from E)
  if (tid < 64) {                         // 1/rowsum for this block's 64 rows
    const float* rp = rowpart + (size_t)h*8*TT + t0 + tid;
    float rs = 0.f;
    #pragma unroll
    for (int sx = 0; sx < 8; ++sx) rs += rp[(size_t)sx*TT];
    invs[tid] = 1.0f / rs;
  }
  __syncthreads();
  #pragma unroll
  for (int m = 0; m < 2; ++m)
    #pragma unroll
    for (int n = 0; n < 4; ++n) {
      const int tb = wr*32 + m*16 + cr;
      const int cl = wc*64 + n*16 + cc;
      #pragma unroll
      for (int r = 0; r < 4; ++r)
        E[(tb + r)*136 + cl] = f2bf(acc[m][n][r] * invs[tb + r]);
    }
  __syncthreads();
  #pragma unroll
  for (int i = 0; i < 4; ++i) {
    int s = tid + 256*i;
    int tl = s >> 4, c8 = (s & 15)*8;
    ulonglong2 v = *(const ulonglong2*)(&E[tl*136 + c8]);
    *(ulonglong2*)(aoH + ((size_t)h*TT + t0 + tl)*768 + c0 + c8) = v;   // full-line writes
  }
}

// ---------------- K3: out-proj as 16 plane-GEMMs over head-major aoH ----------------
// grid (16 t-tiles(64), 16 j, nb); K = 8 head-chunks x 96 ([ao_j(h) | ao_srcj(h)])
__global__ __launch_bounds__(256) void k3_mfma(const ushort* __restrict__ aoH0,
                                               const ushort* __restrict__ wBt,
                                               const float* __restrict__ b_next,
                                               const float* __restrict__ hidden,
                                               float* __restrict__ out, int b0) {
  const int lb = blockIdx.z;
  const ushort* aoH = aoH0 + (size_t)lb*AO_S;
  const float* hidden_b = hidden + (size_t)(b0 + lb)*TT*768;
  float* out_b = out + (size_t)(b0 + lb)*TT*768;
  const int j = blockIdx.y, t0 = blockIdx.x*64;
  const int srcj = c_srcj[j];
  __shared__ __align__(16) ushort As[64*104];
  __shared__ __align__(16) ushort Bs[48*104];
  const int tid = threadIdx.x;
  const int lane = tid & 63, wid = tid >> 6;
  const int rr = lane & 15, kq = lane >> 4;
  const ushort* bw = wBt + (size_t)j*48*768;
  const int ar = tid >> 2, aq = tid & 3;       // stage: 4 thr/row, 3 chunks each
  f32x4 acc[3] = {};
  for (int hh = 0; hh < HH; ++hh) {
    __syncthreads();
    {
      const ushort* rowp = aoH + ((size_t)hh*TT + t0 + ar)*768;
      #pragma unroll
      for (int q = 0; q < 3; ++q) {
        int ci = aq*3 + q;                     // 0..11
        const ushort* src = rowp + ((ci < 6) ? (j*48 + ci*8) : (srcj*48 + (ci - 6)*8));
        *(ulonglong2*)(&As[ar*104 + ci*8]) = *(const ulonglong2*)src;
      }
      if (tid < 192) {
        const ushort* brow = bw + (size_t)ar*768 + hh*96;
        #pragma unroll
        for (int q = 0; q < 3; ++q) {
          int ci = aq*3 + q;
          *(ulonglong2*)(&Bs[ar*104 + ci*8]) = *(const ulonglong2*)(brow + ci*8);
        }
      }
    }
    __syncthreads();
    #pragma unroll
    for (int ks = 0; ks < 3; ++ks) {
      bf16x8 af = *(const bf16x8*)(&As[(wid*16 + rr)*104 + ks*32 + kq*8]);
      #pragma unroll
      for (int n = 0; n < 3; ++n) {
        bf16x8 bf = *(const bf16x8*)(&Bs[(n*16 + rr)*104 + ks*32 + kq*8]);
        acc[n] = __builtin_amdgcn_mfma_f32_16x16x32_bf16(af, bf, acc[n], 0, 0, 0);
      }
    }
  }
  const int cr = (lane >> 4) << 2, cc = lane & 15;
  #pragma unroll
  for (int n = 0; n < 3; ++n) {
    int o = n*16 + cc;
    float bb = (j == 0) ? b_next[o] : 0.f;
    #pragma unroll
    for (int r = 0; r < 4; ++r) {
      int t = t0 + wid*16 + cr + r;
      size_t off = (size_t)t*768 + o*16 + j;
      out_b[off] = acc[n][r] + bb + hidden_b[off];
    }
  }
}

extern "C" void kernel_launch(void* const* d_in, const int* in_sizes, int n_in,
                              void* d_out, int out_size, void* d_ws, size_t ws_size,
                              hipStream_t stream) {
  const float* hidden = (const float*)d_in[0];
  const float* w_attn = (const float*)d_in[1];
  const float* b_attn = (const float*)d_in[2];
  const float* w_next = (const float*)d_in[3];
  const float* b_next = (const float*)d_in[4];
  const float* ln_w   = (const float*)d_in[5];
  float* out = (float*)d_out;
  float* ws = (float*)d_ws;

  const size_t W_FL = (16*48*768 + 16*1152*96)/2;   // wBt + wB in floats = 589,824
  // nb capped at 2: per-iteration working set ~155 MB fits the 256 MB L3, so
  // k2d's 6x U re-reads + k2b panel re-reads become L3 hits (r16: 309 MB HBM FETCH
  // because the nb=4 set ~280 MB spilled L3).
  int nb = 0;
  for (int g = 2; g >= 1; g >>= 1) {
    size_t need = ((size_t)g*(U_S/2 + RP_S + QF_S /*qf+kf in fl*/ + VT_S/2 + AO_S/2 + HTB_S/2) + W_FL)*4;
    if (ws_size >= need) { nb = g; break; }
  }
  if (nb == 0) {
    kfill<<<2048, 256, 0, stream>>>(out, (size_t)out_size, 1.0e6f);
    return;
  }

  // layout (ushort* unless noted); strides per batch
  ushort* ubuf    = (ushort*)ws;                                  // nb * U_S
  float*  rowpart = ws + (size_t)nb*(U_S/2);                      // nb * RP_S f32
  ushort* qf      = (ushort*)(rowpart + (size_t)nb*RP_S);         // nb * QF_S
  ushort* kf      = qf + (size_t)nb*QF_S;                         // nb * QF_S
  ushort* vT      = kf + (size_t)nb*QF_S;                         // nb * VT_S
  ushort* aoH     = vT + (size_t)nb*VT_S;                         // nb * AO_S
  ushort* hTb     = aoH + (size_t)nb*AO_S;                        // nb * HTB_S
  ushort* wBt     = hTb + (size_t)nb*HTB_S;                       // 16*48*768
  ushort* wB      = wBt + (size_t)16*48*768;                      // 16*1152*96

  k0b_wplanes<<<1152, 256, 0, stream>>>(w_next, wBt);
  k0c_wqkv<<<3456, 256, 0, stream>>>(w_attn, wB);
  for (int b0 = 0; b0 < BB; b0 += nb) {
    k1_rmsnorm<<<dim3(TT, nb), 256, 0, stream>>>(hidden, ln_w, hTb, b0);
    k1b_qkv_mfma<<<dim3(8, 9, 16*nb), 256, 0, stream>>>(hTb, wB, b_attn, qf, kf, vT);
    k1c_extras<<<dim3(THD_B/4, nb), 256, 0, stream>>>(qf, kf);
    k2b_logits_mfma<<<dim3(8, 16, 8*nb), 256, 0, stream>>>(qf, kf, ubuf, rowpart);
    k2d_pv_mfma<<<dim3(6, 16, 8*nb), 256, 0, stream>>>(ubuf, vT, rowpart, aoH);
    k3_mfma<<<dim3(16, 16, nb), 256, 0, stream>>>(aoH, wBt, b_next, hidden, out, b0);
  }
}

// Round 19
// 272.162 us; speedup vs baseline: 1.7510x; 1.1154x over previous
//
#include <hip/hip_runtime.h>
#include <math.h>

#define BB 4
#define TT 1024
#define CC 48
#define HH 8
#define THD_B (HH*TT)     // 8192 token-heads per batch
#define FF 576            // padded feature dim (528 bilinear + qn/kn + pad), 9*64
#define CK (CC*16)        // 768

// per-batch buffer strides in ushorts (f32 for rowpart)
#define QF_S  ((size_t)THD_B*FF)     // 4,718,592
#define VT_S  ((size_t)THD_B*CK)     // 6,291,456
#define AO_S  ((size_t)HH*TT*768)    // 6,291,456
#define U_S   ((size_t)HH*TT*TT)     // 8,388,608
#define RP_S  ((size_t)HH*8*TT)      // 65,536 f32
#define HTB_S ((size_t)16*TT*48)     // 786,432

typedef __attribute__((ext_vector_type(8))) short bf16x8;
typedef __attribute__((ext_vector_type(4))) float f32x4;

// per-component tables: grade slice, e0 slice, e0 source comp, feature index
// e0 maps move s->d: 0->1, 2->5, 3->6, 4->7, 8->11, 9->12, 10->13, 14->15
__constant__ int c_gj[16]   = {0,1,1,1,1,2,2,2,2,2,2,3,3,3,3,4};
__constant__ int c_ej[16]   = {-1,5,-1,-1,-1,6,6,6,-1,-1,-1,7,7,7,-1,8};
__constant__ int c_srcj[16] = {0,0,0,0,0,2,3,4,0,0,0,8,9,10,0,14};
__constant__ int c_fi[16]   = {0,-1,1,2,3,-1,-1,-1,4,5,6,8,9,10,7,-1};

__device__ inline ushort f2bf(float x) {           // RNE float->bf16
  union { float f; unsigned u; } a; a.f = x;
  unsigned r = a.u + 0x7FFFu + ((a.u >> 16) & 1u);
  return (ushort)(r >> 16);
}
__device__ inline float bf2f(ushort u) {
  union { unsigned u; float f; } a; a.u = ((unsigned)u) << 16; return a.f;
}
// LDS tile [rows][64 ushorts]; 16B-chunk XOR swizzle on low 2 bits (involution)
__device__ inline int swz64(int row, int chunk) {
  return row*64 + (((chunk & 4) | ((chunk ^ (row >> 2)) & 3)) << 3);
}
// async global->LDS, 16B per lane; LDS dest = uniform base + lane*16 (linear).
// Swizzle realized by pre-permuting the per-lane GLOBAL source chunk (rule #21).
__device__ inline void glds16(const ushort* g, ushort* l) {
  __builtin_amdgcn_global_load_lds((const __attribute__((address_space(1))) void*)g,
                                   (__attribute__((address_space(3))) void*)l, 16, 0, 0);
}

// ---------------- sentinel fill (workspace too small diagnostic) ----------------
__global__ void kfill(float* __restrict__ p, size_t n, float v) {
  size_t i = (size_t)blockIdx.x*256 + threadIdx.x;
  size_t stride = (size_t)gridDim.x*256;
  for (; i < n; i += stride) p[i] = v;
}

// ---------------- K0b: out-proj weights, bf16, [j][o][k], k = h*96 + {g | e} ----------------
__global__ void k0b_wplanes(const float* __restrict__ w_next,
                            ushort* __restrict__ wBt) {
  int idx = blockIdx.x*256 + threadIdx.x;   // over 16*48*384
  if (idx >= 16*48*384) return;
  int j = idx / (48*384), rem = idx % (48*384), o = rem / 384, i = rem % 384;
  int h = i / 48, c = i % 48;
  int g = c_gj[j], e = c_ej[j];
  ushort* dst = wBt + ((size_t)j*48 + o)*768;
  dst[h*96 + c]      = f2bf(w_next[((size_t)o*384 + i)*9 + g]);
  dst[h*96 + 48 + c] = (e >= 0) ? f2bf(w_next[((size_t)o*384 + i)*9 + e]) : (ushort)0;
}

// ---------------- K0c: per-plane qkv weights, bf16, [j][o(1152)][96] ----------------
__global__ void k0c_wqkv(const float* __restrict__ w_attn,
                         ushort* __restrict__ wB) {
  int idx = blockIdx.x*256 + threadIdx.x;   // over 16*1152*48
  if (idx >= 16*1152*48) return;
  int j = idx / (1152*48), rem = idx % (1152*48), o = rem / 48, i = rem % 48;
  int g = c_gj[j], e = c_ej[j];
  float scl = (j >= 11 && j <= 13 && o < 768) ? 1.41421356237f : 1.0f;
  ushort* dst = wB + ((size_t)j*1152 + o)*96;
  dst[i]      = f2bf(w_attn[((size_t)o*48 + i)*9 + g] * scl);
  dst[48 + i] = (e >= 0) ? f2bf(w_attn[((size_t)o*48 + i)*9 + e] * scl) : (ushort)0;
}

// ---------------- K1: equi RMS norm -> hTb[comp][token][chan] (bf16), grid (TT, nb) ----------------
__global__ __launch_bounds__(256) void k1_rmsnorm(const float* __restrict__ hidden,
                                                  const float* __restrict__ lnw,
                                                  ushort* __restrict__ hTb0, int b0) {
  const int lb = blockIdx.y;
  const float* hidden_b = hidden + (size_t)(b0 + lb)*TT*768;
  ushort* hTb = hTb0 + (size_t)lb*HTB_S;
  int n = blockIdx.x, tid = threadIdx.x;
  __shared__ float xs[768];
  __shared__ float red[256];
  float psum = 0.f;
  for (int e = tid; e < 768; e += 256) {
    float v = hidden_b[(size_t)n*768 + e];
    xs[e] = v;
    int k = e & 15;
    if ((0x471Du >> k) & 1u) psum += v*v;   // INV = {0,2,3,4,8,9,10,14}
  }
  red[tid] = psum;
  __syncthreads();
  for (int s = 128; s > 0; s >>= 1) { if (tid < s) red[tid] += red[tid+s]; __syncthreads(); }
  float scale = rsqrtf(red[0]/48.0f + 1e-6f);
  for (int e = tid; e < 768; e += 256) {
    int k = e / 48, i = e % 48;
    hTb[((size_t)k*TT + n)*48 + i] = f2bf(xs[i*16 + k] * scale * lnw[i]);
  }
}

// ---------------- K1b: qkv equi-linear, bf16 MFMA plane-GEMMs ----------------
// grid (8 t-tiles(128), 9 o-tiles(128), nb*16); z = lb*16 + j
__global__ __launch_bounds__(256) void k1b_qkv_mfma(const ushort* __restrict__ hTb0,
                                                    const ushort* __restrict__ wB,
                                                    const float* __restrict__ b_attn,
                                                    ushort* __restrict__ qf0,
                                                    ushort* __restrict__ kf0,
                                                    ushort* __restrict__ vT0) {
  const int j = blockIdx.z & 15, lb = blockIdx.z >> 4;
  const int oy = blockIdx.y;
  const int fi = c_fi[j];
  if (fi < 0 && oy < 6) return;            // q/k never use comps {1,5,6,7,15}
  const ushort* hTb = hTb0 + (size_t)lb*HTB_S;
  ushort* qf = qf0 + (size_t)lb*QF_S;
  ushort* kf = kf0 + (size_t)lb*QF_S;
  ushort* vT = vT0 + (size_t)lb*VT_S;
  const int t0 = blockIdx.x*128, o0 = oy*128;
  const int srcj = c_srcj[j];
  __shared__ __align__(16) ushort smem[2*128*104];   // As | Bs, reused as E
  ushort* As = smem;
  ushort* Bs = smem + 128*104;
  const int tid = threadIdx.x;
  const int lane = tid & 63, wid = tid >> 6;
  const int wr = wid >> 1, wc = wid & 1;
  const int rr = lane & 15, kq = lane >> 4;
  {
    const int r = tid >> 1, half = tid & 1;
    const ushort* sa = hTb + ((size_t)(half ? srcj : j)*TT + t0 + r)*48;
    const ushort* sb = wB + ((size_t)j*1152 + o0 + r)*96 + half*48;
    #pragma unroll
    for (int i = 0; i < 6; ++i) {          // 48 ushorts = 6 x 16B chunks
      *(ulonglong2*)(&As[r*104 + half*48 + i*8]) = *(const ulonglong2*)(sa + i*8);
      *(ulonglong2*)(&Bs[r*104 + half*48 + i*8]) = *(const ulonglong2*)(sb + i*8);
    }
  }
  __syncthreads();
  f32x4 acc[4][4] = {};
  #pragma unroll
  for (int ks = 0; ks < 3; ++ks) {
    bf16x8 af[4], bfv[4];
    #pragma unroll
    for (int m = 0; m < 4; ++m)
      af[m] = *(const bf16x8*)(&As[(wr*64 + m*16 + rr)*104 + ks*32 + kq*8]);
    #pragma unroll
    for (int n = 0; n < 4; ++n)
      bfv[n] = *(const bf16x8*)(&Bs[(wc*64 + n*16 + rr)*104 + ks*32 + kq*8]);
    #pragma unroll
    for (int m = 0; m < 4; ++m)
      #pragma unroll
      for (int n = 0; n < 4; ++n)
        acc[m][n] = __builtin_amdgcn_mfma_f32_16x16x32_bf16(af[m], bfv[n], acc[m][n], 0, 0, 0);
  }
  const int cr = (lane >> 4) << 2, cc = lane & 15;
  __syncthreads();                         // all frag reads done -> reuse smem
  ushort* E = smem;                        // 128x136 ushorts
  if (oy < 6) {
    // q/k: E[t][o] (pad 136), scatter 2B writes, coalesced row reads
    #pragma unroll
    for (int n = 0; n < 4; ++n) {
      const int ol = wc*64 + n*16 + cc;
      const float bias = (j == 0) ? b_attn[o0 + ol] : 0.f;
      #pragma unroll
      for (int m = 0; m < 4; ++m) {
        const int tb = wr*64 + m*16 + cr;
        #pragma unroll
        for (int r = 0; r < 4; ++r)
          E[(tb + r)*136 + ol] = f2bf(acc[m][n][r] + bias);
      }
    }
    __syncthreads();
    #pragma unroll
    for (int i = 0; i < 8; ++i) {
      int s = tid + 256*i;
      int tl = s >> 4, o8 = (s & 15)*8;
      ulonglong2 v = *(const ulonglong2*)(&E[tl*136 + o8]);
      int og = o0 + o8;
      int qkv = og / 384, rem = og % 384, head = rem / 48, c = rem % 48;
      ushort* dst = (qkv == 0 ? qf : kf) + ((size_t)head*TT + t0 + tl)*FF + fi*48 + c;
      *(ulonglong2*)dst = v;
    }
  } else {
    // v: E[o][t] (pad 136), packed 8B writes, coalesced t-row reads -> vT direct
    #pragma unroll
    for (int n = 0; n < 4; ++n) {
      const int ol = wc*64 + n*16 + cc;
      const float bias = (j == 0) ? b_attn[o0 + ol] : 0.f;
      #pragma unroll
      for (int m = 0; m < 4; ++m) {
        const int tb = wr*64 + m*16 + cr;
        uint2 pk;
        pk.x = (uint)f2bf(acc[m][n][0] + bias) | ((uint)f2bf(acc[m][n][1] + bias) << 16);
        pk.y = (uint)f2bf(acc[m][n][2] + bias) | ((uint)f2bf(acc[m][n][3] + bias) << 16);
        *(uint2*)(&E[ol*136 + tb]) = pk;
      }
    }
    __syncthreads();
    #pragma unroll
    for (int i = 0; i < 8; ++i) {
      int s = tid + 256*i;
      int ol = s >> 4, t8 = (s & 15)*8;
      ulonglong2 v = *(const ulonglong2*)(&E[ol*136 + t8]);
      int og = o0 + ol;
      int rem = og % 384, head = rem / 48, c = rem % 48;
      ushort* dst = vT + ((size_t)((head*16 + j)*48 + c))*TT + t0 + t8;
      *(ulonglong2*)dst = v;
    }
  }
}

// ---------------- K1c: qn/kn rank-1 features, one wave per token-head; grid (THD_B/4, nb) ----------------
__global__ __launch_bounds__(256) void k1c_extras(ushort* __restrict__ qf0,
                                                  ushort* __restrict__ kf0) {
  const int lb = blockIdx.y;
  int th = blockIdx.x*4 + (threadIdx.x >> 6);
  int lane = threadIdx.x & 63;
  ushort* q = qf0 + (size_t)lb*QF_S + (size_t)th*FF;
  ushort* k = kf0 + (size_t)lb*QF_S + (size_t)th*FF;
  float qn = 0.f, kn = 0.f;
  if (lane < 36) {                       // elements 384..527 (sqrt2*proj planes)
    ushort4 a = *(const ushort4*)(q + 384 + lane*4);
    ushort4 b = *(const ushort4*)(k + 384 + lane*4);
    float x;
    x = bf2f(a.x); qn += x*x;  x = bf2f(a.y); qn += x*x;
    x = bf2f(a.z); qn += x*x;  x = bf2f(a.w); qn += x*x;
    x = bf2f(b.x); kn += x*x;  x = bf2f(b.y); kn += x*x;
    x = bf2f(b.z); kn += x*x;  x = bf2f(b.w); kn += x*x;
  }
  #pragma unroll
  for (int off = 32; off; off >>= 1) {
    qn += __shfl_xor(qn, off, 64);
    kn += __shfl_xor(kn, off, 64);
  }
  if (lane == 0) {                       // features hold sqrt(2)*proj -> *0.5
    q[528] = f2bf(qn*0.5f); q[529] = 0x3F80u;      // 1.0
    k[528] = 0xBF80u;       k[529] = f2bf(-kn*0.5f);
  }
  if (lane < 46) { q[530+lane] = 0; k[530+lane] = 0; }  // zero pad to FF=576
}

// ---------------- K2b: U = exp((qf.kf)/sqrt(384)) bf16 + per-tile row sums ----------------
// grid (8 s-tiles(128), 16 t-tiles(64), nb*8); z = lb*8 + h. Bounded logits -> no max-sub.
__global__ __launch_bounds__(256) void k2b_logits_mfma(const ushort* __restrict__ qf0,
                                                       const ushort* __restrict__ kf0,
                                                       ushort* __restrict__ ubuf0,
                                                       float* __restrict__ rowpart0) {
  const int h = blockIdx.z & 7, lb = blockIdx.z >> 3;
  const int t0 = blockIdx.y*64, s0 = blockIdx.x*128;
  const ushort* Ag = qf0 + (size_t)lb*QF_S + (size_t)h*TT*FF;
  const ushort* Bg = kf0 + (size_t)lb*QF_S + (size_t)h*TT*FF;
  ushort* ubuf = ubuf0 + (size_t)lb*U_S;
  float* rowpart = rowpart0 + (size_t)lb*RP_S;
  __shared__ __align__(16) ushort smem[64*64 + 128*64];   // As | Bs (24KB); E reuse 64*136
  ushort* As = smem;
  ushort* Bs = smem + 64*64;
  const int tid = threadIdx.x;
  const int lane = tid & 63, wid = tid >> 6;
  const int wr = wid >> 1, wc = wid & 1;           // wave = 32t x 64s
  const int rr = lane & 15, kq = lane >> 4;
  const int lr8 = lane >> 3, ch = lane & 7;        // staging lane -> row/chunk
  f32x4 acc[2][4] = {};
  for (int kk = 0; kk < FF; kk += 64) {
    __syncthreads();
    #pragma unroll
    for (int i = 0; i < 2; ++i) {                  // A: 64 rows, 16/wave
      int r = wid*16 + i*8 + lr8;
      int sch = (ch & 4) | ((ch ^ (r >> 2)) & 3);
      glds16(Ag + (size_t)(t0 + r)*FF + kk + sch*8, &As[(wid*16 + i*8)*64]);
    }
    #pragma unroll
    for (int i = 0; i < 4; ++i) {                  // B: 128 rows, 32/wave
      int r = wid*32 + i*8 + lr8;
      int sch = (ch & 4) | ((ch ^ (r >> 2)) & 3);
      glds16(Bg + (size_t)(s0 + r)*FF + kk + sch*8, &Bs[(wid*32 + i*8)*64]);
    }
    __syncthreads();                               // drains vmcnt -> LDS valid
    #pragma unroll
    for (int ks = 0; ks < 2; ++ks) {
      bf16x8 af[2], bfv[4];
      #pragma unroll
      for (int m = 0; m < 2; ++m) af[m]  = *(const bf16x8*)(&As[swz64(wr*32 + m*16 + rr, ks*4 + kq)]);
      #pragma unroll
      for (int n = 0; n < 4; ++n) bfv[n] = *(const bf16x8*)(&Bs[swz64(wc*64 + n*16 + rr, ks*4 + kq)]);
      #pragma unroll
      for (int m = 0; m < 2; ++m)
        #pragma unroll
        for (int n = 0; n < 4; ++n)
          acc[m][n] = __builtin_amdgcn_mfma_f32_16x16x32_bf16(af[m], bfv[n], acc[m][n], 0, 0, 0);
    }
  }
  const float iscl = 0.051031036307982884f;   // 1/sqrt(384)
  const int cr = (lane >> 4) << 2, cc = lane & 15;
  __syncthreads();
  ushort* E = smem;                           // [64][136] = 8704 ushorts
  float* part = (float*)(smem + 8704);        // 256 f32 (disjoint from E)
  #pragma unroll
  for (int m = 0; m < 2; ++m)
    #pragma unroll
    for (int n = 0; n < 4; ++n) {
      const int tb = wr*32 + m*16 + cr;
      const int sl = wc*64 + n*16 + cc;
      #pragma unroll
      for (int r = 0; r < 4; ++r)
        E[(tb + r)*136 + sl] = f2bf(__expf(acc[m][n][r]*iscl));
    }
  __syncthreads();
  {                                           // per-row segment sums (row = tid>>2)
    const int row = tid >> 2, q4 = tid & 3;
    const ushort* er = &E[row*136 + q4*32];
    float seg = 0.f;
    #pragma unroll
    for (int i = 0; i < 4; ++i) {
      ulonglong2 v = *(const ulonglong2*)(er + i*8);
      const ushort* u = (const ushort*)&v;
      #pragma unroll
      for (int jj = 0; jj < 8; ++jj) seg += bf2f(u[jj]);
    }
    part[tid] = seg;
  }
  #pragma unroll
  for (int i = 0; i < 4; ++i) {               // stream U out
    int s = tid + 256*i;
    int tl = s >> 4, s8 = (s & 15)*8;
    ulonglong2 v = *(const ulonglong2*)(&E[tl*136 + s8]);
    *(ulonglong2*)(ubuf + ((size_t)h*TT + t0 + tl)*TT + s0 + s8) = v;
  }
  __syncthreads();
  if (tid < 64)
    rowpart[((size_t)h*8 + blockIdx.x)*TT + t0 + tid] =
        part[tid*4] + part[tid*4+1] + part[tid*4+2] + part[tid*4+3];
}

// ---------------- K2d: aoH[h][t][cg] = (U @ V) / rowsum, bf16 MFMA, BK=64 ----------------
// grid (3 c-tiles(256), 16 t-tiles(64), nb*8), 512 thr = 8 waves (2x4).
// c-tile 256: U row-panel fetched 3x instead of 6x (r18: U re-read is the FETCH driver).
__global__ __launch_bounds__(512) void k2d_pv_mfma(const ushort* __restrict__ ubuf0,
                                                   const ushort* __restrict__ vT0,
                                                   const float* __restrict__ rowpart0,
                                                   ushort* __restrict__ aoH0) {
  const int h = blockIdx.z & 7, lb = blockIdx.z >> 3;
  const int t0 = blockIdx.y*64, c0 = blockIdx.x*256;
  const ushort* Ag = ubuf0 + (size_t)lb*U_S + (size_t)h*TT*TT;
  const ushort* Bg = vT0 + (size_t)lb*VT_S + (size_t)h*CK*TT;
  const float* rowpart = rowpart0 + (size_t)lb*RP_S;
  ushort* aoH = aoH0 + (size_t)lb*AO_S;
  __shared__ __align__(16) ushort smem[64*64 + 256*64];   // As | Bs (40KB); E reuse 64*264
  ushort* As = smem;
  ushort* Bs = smem + 64*64;
  const int tid = threadIdx.x;
  const int lane = tid & 63, wid = tid >> 6;       // 8 waves
  const int wr = wid >> 2, wc = wid & 3;           // wave = 32t x 64c, 2x4 grid
  const int rr = lane & 15, kq = lane >> 4;
  const int lr8 = lane >> 3, ch = lane & 7;
  f32x4 acc[2][4] = {};
  for (int kk = 0; kk < TT; kk += 64) {
    __syncthreads();
    {                                              // A: 64 rows, 8 rows/wave
      int r = wid*8 + lr8;
      int sch = (ch & 4) | ((ch ^ (r >> 2)) & 3);
      glds16(Ag + (size_t)(t0 + r)*TT + kk + sch*8, &As[(wid*8)*64]);
    }
    #pragma unroll
    for (int i = 0; i < 4; ++i) {                  // B: 256 rows, 32/wave
      int r = wid*32 + i*8 + lr8;
      int sch = (ch & 4) | ((ch ^ (r >> 2)) & 3);
      glds16(Bg + (size_t)(c0 + r)*TT + kk + sch*8, &Bs[(wid*32 + i*8)*64]);
    }
    __syncthreads();                               // drains vmcnt -> LDS valid
    #pragma unroll
    for (int ks = 0; ks < 2; ++ks) {
      bf16x8 af[2], bfv[4];
      #pragma unroll
      for (int m = 0; m < 2; ++m) af[m]  = *(const bf16x8*)(&As[swz64(wr*32 + m*16 + rr, ks*4 + kq)]);
      #pragma unroll
      for (int n = 0; n < 4; ++n) bfv[n] = *(const bf16x8*)(&Bs[swz64(wc*64 + n*16 + rr, ks*4 + kq)]);
      #pragma unroll
      for (int m = 0; m < 2; ++m)
        #pragma unroll
        for (int n = 0; n < 4; ++n)
          acc[m][n] = __builtin_amdgcn_mfma_f32_16x16x32_bf16(af[m], bfv[n], acc[m][n], 0, 0, 0);
    }
  }
  const int cr = (lane >> 4) << 2, cc = lane & 15;
  __syncthreads();
  ushort* E = smem;                       // [64][264] = 16896 ushorts
  float* invs = (float*)(smem + 16896);   // 64 f32 (disjoint from E; 17024 <= 20480)
  if (tid < 64) {                         // 1/rowsum for this block's 64 rows
    const float* rp = rowpart + (size_t)h*8*TT + t0 + tid;
    float rs = 0.f;
    #pragma unroll
    for (int sx = 0; sx < 8; ++sx) rs += rp[(size_t)sx*TT];
    invs[tid] = 1.0f / rs;
  }
  __syncthreads();
  #pragma unroll
  for (int m = 0; m < 2; ++m)
    #pragma unroll
    for (int n = 0; n < 4; ++n) {
      const int tb = wr*32 + m*16 + cr;
      const int cl = wc*64 + n*16 + cc;
      #pragma unroll
      for (int r = 0; r < 4; ++r)
        E[(tb + r)*264 + cl] = f2bf(acc[m][n][r] * invs[tb + r]);
    }
  __syncthreads();
  #pragma unroll
  for (int i = 0; i < 4; ++i) {
    int s = tid + 512*i;                  // 2048 16B-chunks
    int tl = s >> 5, c8 = (s & 31)*8;
    ulonglong2 v = *(const ulonglong2*)(&E[tl*264 + c8]);
    *(ulonglong2*)(aoH + ((size_t)h*TT + t0 + tl)*768 + c0 + c8) = v;   // full-line writes
  }
}

// ---------------- K3: out-proj as 16 plane-GEMMs over head-major aoH ----------------
// grid (16 t-tiles(64), 16 j, nb); K = 8 head-chunks x 96 ([ao_j(h) | ao_srcj(h)])
__global__ __launch_bounds__(256) void k3_mfma(const ushort* __restrict__ aoH0,
                                               const ushort* __restrict__ wBt,
                                               const float* __restrict__ b_next,
                                               const float* __restrict__ hidden,
                                               float* __restrict__ out, int b0) {
  const int lb = blockIdx.z;
  const ushort* aoH = aoH0 + (size_t)lb*AO_S;
  const float* hidden_b = hidden + (size_t)(b0 + lb)*TT*768;
  float* out_b = out + (size_t)(b0 + lb)*TT*768;
  const int j = blockIdx.y, t0 = blockIdx.x*64;
  const int srcj = c_srcj[j];
  __shared__ __align__(16) ushort As[64*104];
  __shared__ __align__(16) ushort Bs[48*104];
  const int tid = threadIdx.x;
  const int lane = tid & 63, wid = tid >> 6;
  const int rr = lane & 15, kq = lane >> 4;
  const ushort* bw = wBt + (size_t)j*48*768;
  const int ar = tid >> 2, aq = tid & 3;       // stage: 4 thr/row, 3 chunks each
  f32x4 acc[3] = {};
  for (int hh = 0; hh < HH; ++hh) {
    __syncthreads();
    {
      const ushort* rowp = aoH + ((size_t)hh*TT + t0 + ar)*768;
      #pragma unroll
      for (int q = 0; q < 3; ++q) {
        int ci = aq*3 + q;                     // 0..11
        const ushort* src = rowp + ((ci < 6) ? (j*48 + ci*8) : (srcj*48 + (ci - 6)*8));
        *(ulonglong2*)(&As[ar*104 + ci*8]) = *(const ulonglong2*)src;
      }
      if (tid < 192) {
        const ushort* brow = bw + (size_t)ar*768 + hh*96;
        #pragma unroll
        for (int q = 0; q < 3; ++q) {
          int ci = aq*3 + q;
          *(ulonglong2*)(&Bs[ar*104 + ci*8]) = *(const ulonglong2*)(brow + ci*8);
        }
      }
    }
    __syncthreads();
    #pragma unroll
    for (int ks = 0; ks < 3; ++ks) {
      bf16x8 af = *(const bf16x8*)(&As[(wid*16 + rr)*104 + ks*32 + kq*8]);
      #pragma unroll
      for (int n = 0; n < 3; ++n) {
        bf16x8 bf = *(const bf16x8*)(&Bs[(n*16 + rr)*104 + ks*32 + kq*8]);
        acc[n] = __builtin_amdgcn_mfma_f32_16x16x32_bf16(af, bf, acc[n], 0, 0, 0);
      }
    }
  }
  const int cr = (lane >> 4) << 2, cc = lane & 15;
  #pragma unroll
  for (int n = 0; n < 3; ++n) {
    int o = n*16 + cc;
    float bb = (j == 0) ? b_next[o] : 0.f;
    #pragma unroll
    for (int r = 0; r < 4; ++r) {
      int t = t0 + wid*16 + cr + r;
      size_t off = (size_t)t*768 + o*16 + j;
      out_b[off] = acc[n][r] + bb + hidden_b[off];
    }
  }
}

extern "C" void kernel_launch(void* const* d_in, const int* in_sizes, int n_in,
                              void* d_out, int out_size, void* d_ws, size_t ws_size,
                              hipStream_t stream) {
  const float* hidden = (const float*)d_in[0];
  const float* w_attn = (const float*)d_in[1];
  const float* b_attn = (const float*)d_in[2];
  const float* w_next = (const float*)d_in[3];
  const float* b_next = (const float*)d_in[4];
  const float* ln_w   = (const float*)d_in[5];
  float* out = (float*)d_out;
  float* ws = (float*)d_ws;

  const size_t W_FL = (16*48*768 + 16*1152*96)/2;   // wBt + wB in floats = 589,824
  // nb=4 restored: r18 proved the nb=2 cap regressed (U re-reads scale with work,
  // not absorbed by L3; fewer fused batches just doubled dispatch overhead).
  int nb = 0;
  for (int g = 4; g >= 1; g >>= 1) {
    size_t need = ((size_t)g*(U_S/2 + RP_S + QF_S /*qf+kf in fl*/ + VT_S/2 + AO_S/2 + HTB_S/2) + W_FL)*4;
    if (ws_size >= need) { nb = g; break; }
  }
  if (nb == 0) {
    kfill<<<2048, 256, 0, stream>>>(out, (size_t)out_size, 1.0e6f);
    return;
  }

  // layout (ushort* unless noted); strides per batch
  ushort* ubuf    = (ushort*)ws;                                  // nb * U_S
  float*  rowpart = ws + (size_t)nb*(U_S/2);                      // nb * RP_S f32
  ushort* qf      = (ushort*)(rowpart + (size_t)nb*RP_S);         // nb * QF_S
  ushort* kf      = qf + (size_t)nb*QF_S;                         // nb * QF_S
  ushort* vT      = kf + (size_t)nb*QF_S;                         // nb * VT_S
  ushort* aoH     = vT + (size_t)nb*VT_S;                         // nb * AO_S
  ushort* hTb     = aoH + (size_t)nb*AO_S;                        // nb * HTB_S
  ushort* wBt     = hTb + (size_t)nb*HTB_S;                       // 16*48*768
  ushort* wB      = wBt + (size_t)16*48*768;                      // 16*1152*96

  k0b_wplanes<<<1152, 256, 0, stream>>>(w_next, wBt);
  k0c_wqkv<<<3456, 256, 0, stream>>>(w_attn, wB);
  for (int b0 = 0; b0 < BB; b0 += nb) {
    k1_rmsnorm<<<dim3(TT, nb), 256, 0, stream>>>(hidden, ln_w, hTb, b0);
    k1b_qkv_mfma<<<dim3(8, 9, 16*nb), 256, 0, stream>>>(hTb, wB, b_attn, qf, kf, vT);
    k1c_extras<<<dim3(THD_B/4, nb), 256, 0, stream>>>(qf, kf);
    k2b_logits_mfma<<<dim3(8, 16, 8*nb), 256, 0, stream>>>(qf, kf, ubuf, rowpart);
    k2d_pv_mfma<<<dim3(3, 16, 8*nb), 512, 0, stream>>>(ubuf, vT, rowpart, aoH);
    k3_mfma<<<dim3(16, 16, nb), 256, 0, stream>>>(aoH, wBt, b_next, hidden, out, b0);
  }
}

// Round 20
// 260.477 us; speedup vs baseline: 1.8295x; 1.0449x over previous
//
#include <hip/hip_runtime.h>
#include <math.h>

#define BB 4
#define TT 1024
#define CC 48
#define HH 8
#define THD_B (HH*TT)     // 8192 token-heads per batch
#define FF 576            // padded feature dim (528 bilinear + qn/kn + pad), 9*64
#define CK (CC*16)        // 768

// per-batch buffer strides in ushorts (f32 for rowpart)
#define QF_S  ((size_t)THD_B*FF)     // 4,718,592
#define VT_S  ((size_t)THD_B*CK)     // 6,291,456
#define AO_S  ((size_t)HH*TT*768)    // 6,291,456
#define U_S   ((size_t)HH*TT*TT)     // 8,388,608
#define RP_S  ((size_t)HH*8*TT)      // 65,536 f32
#define HTB_S ((size_t)16*TT*48)     // 786,432

typedef __attribute__((ext_vector_type(8))) short bf16x8;
typedef __attribute__((ext_vector_type(4))) float f32x4;

// per-component tables: grade slice, e0 slice, e0 source comp, feature index
// e0 maps move s->d: 0->1, 2->5, 3->6, 4->7, 8->11, 9->12, 10->13, 14->15
__constant__ int c_gj[16]   = {0,1,1,1,1,2,2,2,2,2,2,3,3,3,3,4};
__constant__ int c_ej[16]   = {-1,5,-1,-1,-1,6,6,6,-1,-1,-1,7,7,7,-1,8};
__constant__ int c_srcj[16] = {0,0,0,0,0,2,3,4,0,0,0,8,9,10,0,14};
__constant__ int c_fi[16]   = {0,-1,1,2,3,-1,-1,-1,4,5,6,8,9,10,7,-1};

__device__ inline ushort f2bf(float x) {           // RNE float->bf16
  union { float f; unsigned u; } a; a.f = x;
  unsigned r = a.u + 0x7FFFu + ((a.u >> 16) & 1u);
  return (ushort)(r >> 16);
}
__device__ inline float bf2f(ushort u) {
  union { unsigned u; float f; } a; a.u = ((unsigned)u) << 16; return a.f;
}
// LDS tile [rows][64 ushorts]; 16B-chunk XOR swizzle on low 2 bits (involution)
__device__ inline int swz64(int row, int chunk) {
  return row*64 + (((chunk & 4) | ((chunk ^ (row >> 2)) & 3)) << 3);
}
// async global->LDS, 16B per lane; LDS dest = uniform base + lane*16 (linear).
// Swizzle realized by pre-permuting the per-lane GLOBAL source chunk (rule #21).
__device__ inline void glds16(const ushort* g, ushort* l) {
  __builtin_amdgcn_global_load_lds((const __attribute__((address_space(1))) void*)g,
                                   (__attribute__((address_space(3))) void*)l, 16, 0, 0);
}

// ---------------- sentinel fill (workspace too small diagnostic) ----------------
__global__ void kfill(float* __restrict__ p, size_t n, float v) {
  size_t i = (size_t)blockIdx.x*256 + threadIdx.x;
  size_t stride = (size_t)gridDim.x*256;
  for (; i < n; i += stride) p[i] = v;
}

// ---------------- K0b: out-proj weights, bf16, [j][o][k], k = h*96 + {g | e} ----------------
__global__ void k0b_wplanes(const float* __restrict__ w_next,
                            ushort* __restrict__ wBt) {
  int idx = blockIdx.x*256 + threadIdx.x;   // over 16*48*384
  if (idx >= 16*48*384) return;
  int j = idx / (48*384), rem = idx % (48*384), o = rem / 384, i = rem % 384;
  int h = i / 48, c = i % 48;
  int g = c_gj[j], e = c_ej[j];
  ushort* dst = wBt + ((size_t)j*48 + o)*768;
  dst[h*96 + c]      = f2bf(w_next[((size_t)o*384 + i)*9 + g]);
  dst[h*96 + 48 + c] = (e >= 0) ? f2bf(w_next[((size_t)o*384 + i)*9 + e]) : (ushort)0;
}

// ---------------- K0c: per-plane qkv weights, bf16, [j][o(1152)][96] ----------------
__global__ void k0c_wqkv(const float* __restrict__ w_attn,
                         ushort* __restrict__ wB) {
  int idx = blockIdx.x*256 + threadIdx.x;   // over 16*1152*48
  if (idx >= 16*1152*48) return;
  int j = idx / (1152*48), rem = idx % (1152*48), o = rem / 48, i = rem % 48;
  int g = c_gj[j], e = c_ej[j];
  float scl = (j >= 11 && j <= 13 && o < 768) ? 1.41421356237f : 1.0f;
  ushort* dst = wB + ((size_t)j*1152 + o)*96;
  dst[i]      = f2bf(w_attn[((size_t)o*48 + i)*9 + g] * scl);
  dst[48 + i] = (e >= 0) ? f2bf(w_attn[((size_t)o*48 + i)*9 + e] * scl) : (ushort)0;
}

// ---------------- K1: equi RMS norm -> hTb[comp][token][chan] (bf16), grid (TT, nb) ----------------
__global__ __launch_bounds__(256) void k1_rmsnorm(const float* __restrict__ hidden,
                                                  const float* __restrict__ lnw,
                                                  ushort* __restrict__ hTb0, int b0) {
  const int lb = blockIdx.y;
  const float* hidden_b = hidden + (size_t)(b0 + lb)*TT*768;
  ushort* hTb = hTb0 + (size_t)lb*HTB_S;
  int n = blockIdx.x, tid = threadIdx.x;
  __shared__ float xs[768];
  __shared__ float red[256];
  float psum = 0.f;
  for (int e = tid; e < 768; e += 256) {
    float v = hidden_b[(size_t)n*768 + e];
    xs[e] = v;
    int k = e & 15;
    if ((0x471Du >> k) & 1u) psum += v*v;   // INV = {0,2,3,4,8,9,10,14}
  }
  red[tid] = psum;
  __syncthreads();
  for (int s = 128; s > 0; s >>= 1) { if (tid < s) red[tid] += red[tid+s]; __syncthreads(); }
  float scale = rsqrtf(red[0]/48.0f + 1e-6f);
  for (int e = tid; e < 768; e += 256) {
    int k = e / 48, i = e % 48;
    hTb[((size_t)k*TT + n)*48 + i] = f2bf(xs[i*16 + k] * scale * lnw[i]);
  }
}

// ---------------- K1b: qkv equi-linear, bf16 MFMA plane-GEMMs ----------------
// grid (8 t-tiles(128), 9 o-tiles(128), nb*16); z = lb*16 + j
__global__ __launch_bounds__(256) void k1b_qkv_mfma(const ushort* __restrict__ hTb0,
                                                    const ushort* __restrict__ wB,
                                                    const float* __restrict__ b_attn,
                                                    ushort* __restrict__ qf0,
                                                    ushort* __restrict__ kf0,
                                                    ushort* __restrict__ vT0) {
  const int j = blockIdx.z & 15, lb = blockIdx.z >> 4;
  const int oy = blockIdx.y;
  const int fi = c_fi[j];
  if (fi < 0 && oy < 6) return;            // q/k never use comps {1,5,6,7,15}
  const ushort* hTb = hTb0 + (size_t)lb*HTB_S;
  ushort* qf = qf0 + (size_t)lb*QF_S;
  ushort* kf = kf0 + (size_t)lb*QF_S;
  ushort* vT = vT0 + (size_t)lb*VT_S;
  const int t0 = blockIdx.x*128, o0 = oy*128;
  const int srcj = c_srcj[j];
  __shared__ __align__(16) ushort smem[2*128*104];   // As | Bs, reused as E
  ushort* As = smem;
  ushort* Bs = smem + 128*104;
  const int tid = threadIdx.x;
  const int lane = tid & 63, wid = tid >> 6;
  const int wr = wid >> 1, wc = wid & 1;
  const int rr = lane & 15, kq = lane >> 4;
  {
    const int r = tid >> 1, half = tid & 1;
    const ushort* sa = hTb + ((size_t)(half ? srcj : j)*TT + t0 + r)*48;
    const ushort* sb = wB + ((size_t)j*1152 + o0 + r)*96 + half*48;
    #pragma unroll
    for (int i = 0; i < 6; ++i) {          // 48 ushorts = 6 x 16B chunks
      *(ulonglong2*)(&As[r*104 + half*48 + i*8]) = *(const ulonglong2*)(sa + i*8);
      *(ulonglong2*)(&Bs[r*104 + half*48 + i*8]) = *(const ulonglong2*)(sb + i*8);
    }
  }
  __syncthreads();
  f32x4 acc[4][4] = {};
  #pragma unroll
  for (int ks = 0; ks < 3; ++ks) {
    bf16x8 af[4], bfv[4];
    #pragma unroll
    for (int m = 0; m < 4; ++m)
      af[m] = *(const bf16x8*)(&As[(wr*64 + m*16 + rr)*104 + ks*32 + kq*8]);
    #pragma unroll
    for (int n = 0; n < 4; ++n)
      bfv[n] = *(const bf16x8*)(&Bs[(wc*64 + n*16 + rr)*104 + ks*32 + kq*8]);
    #pragma unroll
    for (int m = 0; m < 4; ++m)
      #pragma unroll
      for (int n = 0; n < 4; ++n)
        acc[m][n] = __builtin_amdgcn_mfma_f32_16x16x32_bf16(af[m], bfv[n], acc[m][n], 0, 0, 0);
  }
  const int cr = (lane >> 4) << 2, cc = lane & 15;
  __syncthreads();                         // all frag reads done -> reuse smem
  ushort* E = smem;                        // 128x136 ushorts
  if (oy < 6) {
    // q/k: E[t][o] (pad 136), scatter 2B writes, coalesced row reads
    #pragma unroll
    for (int n = 0; n < 4; ++n) {
      const int ol = wc*64 + n*16 + cc;
      const float bias = (j == 0) ? b_attn[o0 + ol] : 0.f;
      #pragma unroll
      for (int m = 0; m < 4; ++m) {
        const int tb = wr*64 + m*16 + cr;
        #pragma unroll
        for (int r = 0; r < 4; ++r)
          E[(tb + r)*136 + ol] = f2bf(acc[m][n][r] + bias);
      }
    }
    __syncthreads();
    #pragma unroll
    for (int i = 0; i < 8; ++i) {
      int s = tid + 256*i;
      int tl = s >> 4, o8 = (s & 15)*8;
      ulonglong2 v = *(const ulonglong2*)(&E[tl*136 + o8]);
      int og = o0 + o8;
      int qkv = og / 384, rem = og % 384, head = rem / 48, c = rem % 48;
      ushort* dst = (qkv == 0 ? qf : kf) + ((size_t)head*TT + t0 + tl)*FF + fi*48 + c;
      *(ulonglong2*)dst = v;
    }
  } else {
    // v: E[o][t] (pad 136), packed 8B writes, coalesced t-row reads -> vT direct
    #pragma unroll
    for (int n = 0; n < 4; ++n) {
      const int ol = wc*64 + n*16 + cc;
      const float bias = (j == 0) ? b_attn[o0 + ol] : 0.f;
      #pragma unroll
      for (int m = 0; m < 4; ++m) {
        const int tb = wr*64 + m*16 + cr;
        uint2 pk;
        pk.x = (uint)f2bf(acc[m][n][0] + bias) | ((uint)f2bf(acc[m][n][1] + bias) << 16);
        pk.y = (uint)f2bf(acc[m][n][2] + bias) | ((uint)f2bf(acc[m][n][3] + bias) << 16);
        *(uint2*)(&E[ol*136 + tb]) = pk;
      }
    }
    __syncthreads();
    #pragma unroll
    for (int i = 0; i < 8; ++i) {
      int s = tid + 256*i;
      int ol = s >> 4, t8 = (s & 15)*8;
      ulonglong2 v = *(const ulonglong2*)(&E[ol*136 + t8]);
      int og = o0 + ol;
      int rem = og % 384, head = rem / 48, c = rem % 48;
      ushort* dst = vT + ((size_t)((head*16 + j)*48 + c))*TT + t0 + t8;
      *(ulonglong2*)dst = v;
    }
  }
}

// ---------------- K1c: qn/kn rank-1 features, one wave per token-head; grid (THD_B/4, nb) ----------------
__global__ __launch_bounds__(256) void k1c_extras(ushort* __restrict__ qf0,
                                                  ushort* __restrict__ kf0) {
  const int lb = blockIdx.y;
  int th = blockIdx.x*4 + (threadIdx.x >> 6);
  int lane = threadIdx.x & 63;
  ushort* q = qf0 + (size_t)lb*QF_S + (size_t)th*FF;
  ushort* k = kf0 + (size_t)lb*QF_S + (size_t)th*FF;
  float qn = 0.f, kn = 0.f;
  if (lane < 36) {                       // elements 384..527 (sqrt2*proj planes)
    ushort4 a = *(const ushort4*)(q + 384 + lane*4);
    ushort4 b = *(const ushort4*)(k + 384 + lane*4);
    float x;
    x = bf2f(a.x); qn += x*x;  x = bf2f(a.y); qn += x*x;
    x = bf2f(a.z); qn += x*x;  x = bf2f(a.w); qn += x*x;
    x = bf2f(b.x); kn += x*x;  x = bf2f(b.y); kn += x*x;
    x = bf2f(b.z); kn += x*x;  x = bf2f(b.w); kn += x*x;
  }
  #pragma unroll
  for (int off = 32; off; off >>= 1) {
    qn += __shfl_xor(qn, off, 64);
    kn += __shfl_xor(kn, off, 64);
  }
  if (lane == 0) {                       // features hold sqrt(2)*proj -> *0.5
    q[528] = f2bf(qn*0.5f); q[529] = 0x3F80u;      // 1.0
    k[528] = 0xBF80u;       k[529] = f2bf(-kn*0.5f);
  }
  if (lane < 46) { q[530+lane] = 0; k[530+lane] = 0; }  // zero pad to FF=576
}

// ---------------- K2b: U = exp((qf.kf)/sqrt(384)) bf16 + per-tile row sums ----------------
// grid (8 s-tiles(128), 16 t-tiles(64), nb*8); z = lb*8 + h. Bounded logits -> no max-sub.
__global__ __launch_bounds__(256) void k2b_logits_mfma(const ushort* __restrict__ qf0,
                                                       const ushort* __restrict__ kf0,
                                                       ushort* __restrict__ ubuf0,
                                                       float* __restrict__ rowpart0) {
  const int h = blockIdx.z & 7, lb = blockIdx.z >> 3;
  const int t0 = blockIdx.y*64, s0 = blockIdx.x*128;
  const ushort* Ag = qf0 + (size_t)lb*QF_S + (size_t)h*TT*FF;
  const ushort* Bg = kf0 + (size_t)lb*QF_S + (size_t)h*TT*FF;
  ushort* ubuf = ubuf0 + (size_t)lb*U_S;
  float* rowpart = rowpart0 + (size_t)lb*RP_S;
  __shared__ __align__(16) ushort smem[64*64 + 128*64];   // As | Bs (24KB); E reuse 64*136
  ushort* As = smem;
  ushort* Bs = smem + 64*64;
  const int tid = threadIdx.x;
  const int lane = tid & 63, wid = tid >> 6;
  const int wr = wid >> 1, wc = wid & 1;           // wave = 32t x 64s
  const int rr = lane & 15, kq = lane >> 4;
  const int lr8 = lane >> 3, ch = lane & 7;        // staging lane -> row/chunk
  f32x4 acc[2][4] = {};
  for (int kk = 0; kk < FF; kk += 64) {
    __syncthreads();
    #pragma unroll
    for (int i = 0; i < 2; ++i) {                  // A: 64 rows, 16/wave
      int r = wid*16 + i*8 + lr8;
      int sch = (ch & 4) | ((ch ^ (r >> 2)) & 3);
      glds16(Ag + (size_t)(t0 + r)*FF + kk + sch*8, &As[(wid*16 + i*8)*64]);
    }
    #pragma unroll
    for (int i = 0; i < 4; ++i) {                  // B: 128 rows, 32/wave
      int r = wid*32 + i*8 + lr8;
      int sch = (ch & 4) | ((ch ^ (r >> 2)) & 3);
      glds16(Bg + (size_t)(s0 + r)*FF + kk + sch*8, &Bs[(wid*32 + i*8)*64]);
    }
    __syncthreads();                               // drains vmcnt -> LDS valid
    #pragma unroll
    for (int ks = 0; ks < 2; ++ks) {
      bf16x8 af[2], bfv[4];
      #pragma unroll
      for (int m = 0; m < 2; ++m) af[m]  = *(const bf16x8*)(&As[swz64(wr*32 + m*16 + rr, ks*4 + kq)]);
      #pragma unroll
      for (int n = 0; n < 4; ++n) bfv[n] = *(const bf16x8*)(&Bs[swz64(wc*64 + n*16 + rr, ks*4 + kq)]);
      #pragma unroll
      for (int m = 0; m < 2; ++m)
        #pragma unroll
        for (int n = 0; n < 4; ++n)
          acc[m][n] = __builtin_amdgcn_mfma_f32_16x16x32_bf16(af[m], bfv[n], acc[m][n], 0, 0, 0);
    }
  }
  const float iscl = 0.051031036307982884f;   // 1/sqrt(384)
  const int cr = (lane >> 4) << 2, cc = lane & 15;
  __syncthreads();
  ushort* E = smem;                           // [64][136] = 8704 ushorts
  float* part = (float*)(smem + 8704);        // 256 f32 (disjoint from E)
  #pragma unroll
  for (int m = 0; m < 2; ++m)
    #pragma unroll
    for (int n = 0; n < 4; ++n) {
      const int tb = wr*32 + m*16 + cr;
      const int sl = wc*64 + n*16 + cc;
      #pragma unroll
      for (int r = 0; r < 4; ++r)
        E[(tb + r)*136 + sl] = f2bf(__expf(acc[m][n][r]*iscl));
    }
  __syncthreads();
  {                                           // per-row segment sums (row = tid>>2)
    const int row = tid >> 2, q4 = tid & 3;
    const ushort* er = &E[row*136 + q4*32];
    float seg = 0.f;
    #pragma unroll
    for (int i = 0; i < 4; ++i) {
      ulonglong2 v = *(const ulonglong2*)(er + i*8);
      const ushort* u = (const ushort*)&v;
      #pragma unroll
      for (int jj = 0; jj < 8; ++jj) seg += bf2f(u[jj]);
    }
    part[tid] = seg;
  }
  #pragma unroll
  for (int i = 0; i < 4; ++i) {               // stream U out
    int s = tid + 256*i;
    int tl = s >> 4, s8 = (s & 15)*8;
    ulonglong2 v = *(const ulonglong2*)(&E[tl*136 + s8]);
    *(ulonglong2*)(ubuf + ((size_t)h*TT + t0 + tl)*TT + s0 + s8) = v;
  }
  __syncthreads();
  if (tid < 64)
    rowpart[((size_t)h*8 + blockIdx.x)*TT + t0 + tid] =
        part[tid*4] + part[tid*4+1] + part[tid*4+2] + part[tid*4+3];
}

// ---------------- K2d: aoH[h][t][cg] = (U @ V) / rowsum, bf16 MFMA, BK=64 ----------------
// 1-D grid nb*8*16*3, chunked-XCD swizzle, c innermost: the 3 c-blocks sharing a U
// row-panel run on ONE XCD (panel fetched once into its L2); a head's 48 blocks are
// contiguous on one XCD so vT (1.5MB, clean) stays L2-resident. 512 thr = 8 waves (2x4).
__global__ __launch_bounds__(512) void k2d_pv_mfma(const ushort* __restrict__ ubuf0,
                                                   const ushort* __restrict__ vT0,
                                                   const float* __restrict__ rowpart0,
                                                   ushort* __restrict__ aoH0) {
  const int q8 = (int)gridDim.x >> 3;
  const int flat = ((int)blockIdx.x & 7)*q8 + ((int)blockIdx.x >> 3);
  const int cx = flat % 3;
  int g = flat / 3;
  const int ty = g & 15; g >>= 4;
  const int h = g & 7;
  const int lb = g >> 3;
  const int t0 = ty*64, c0 = cx*256;
  const ushort* Ag = ubuf0 + (size_t)lb*U_S + (size_t)h*TT*TT;
  const ushort* Bg = vT0 + (size_t)lb*VT_S + (size_t)h*CK*TT;
  const float* rowpart = rowpart0 + (size_t)lb*RP_S;
  ushort* aoH = aoH0 + (size_t)lb*AO_S;
  __shared__ __align__(16) ushort smem[64*64 + 256*64];   // As | Bs (40KB); E reuse 64*264
  ushort* As = smem;
  ushort* Bs = smem + 64*64;
  const int tid = threadIdx.x;
  const int lane = tid & 63, wid = tid >> 6;       // 8 waves
  const int wr = wid >> 2, wc = wid & 3;           // wave = 32t x 64c, 2x4 grid
  const int rr = lane & 15, kq = lane >> 4;
  const int lr8 = lane >> 3, ch = lane & 7;
  f32x4 acc[2][4] = {};
  for (int kk = 0; kk < TT; kk += 64) {
    __syncthreads();
    {                                              // A: 64 rows, 8 rows/wave
      int r = wid*8 + lr8;
      int sch = (ch & 4) | ((ch ^ (r >> 2)) & 3);
      glds16(Ag + (size_t)(t0 + r)*TT + kk + sch*8, &As[(wid*8)*64]);
    }
    #pragma unroll
    for (int i = 0; i < 4; ++i) {                  // B: 256 rows, 32/wave
      int r = wid*32 + i*8 + lr8;
      int sch = (ch & 4) | ((ch ^ (r >> 2)) & 3);
      glds16(Bg + (size_t)(c0 + r)*TT + kk + sch*8, &Bs[(wid*32 + i*8)*64]);
    }
    __syncthreads();                               // drains vmcnt -> LDS valid
    #pragma unroll
    for (int ks = 0; ks < 2; ++ks) {
      bf16x8 af[2], bfv[4];
      #pragma unroll
      for (int m = 0; m < 2; ++m) af[m]  = *(const bf16x8*)(&As[swz64(wr*32 + m*16 + rr, ks*4 + kq)]);
      #pragma unroll
      for (int n = 0; n < 4; ++n) bfv[n] = *(const bf16x8*)(&Bs[swz64(wc*64 + n*16 + rr, ks*4 + kq)]);
      #pragma unroll
      for (int m = 0; m < 2; ++m)
        #pragma unroll
        for (int n = 0; n < 4; ++n)
          acc[m][n] = __builtin_amdgcn_mfma_f32_16x16x32_bf16(af[m], bfv[n], acc[m][n], 0, 0, 0);
    }
  }
  const int cr = (lane >> 4) << 2, cc = lane & 15;
  __syncthreads();
  ushort* E = smem;                       // [64][264] = 16896 ushorts
  float* invs = (float*)(smem + 16896);   // 64 f32 (disjoint from E; 17024 <= 20480)
  if (tid < 64) {                         // 1/rowsum for this block's 64 rows
    const float* rp = rowpart + (size_t)h*8*TT + t0 + tid;
    float rs = 0.f;
    #pragma unroll
    for (int sx = 0; sx < 8; ++sx) rs += rp[(size_t)sx*TT];
    invs[tid] = 1.0f / rs;
  }
  __syncthreads();
  #pragma unroll
  for (int m = 0; m < 2; ++m)
    #pragma unroll
    for (int n = 0; n < 4; ++n) {
      const int tb = wr*32 + m*16 + cr;
      const int cl = wc*64 + n*16 + cc;
      #pragma unroll
      for (int r = 0; r < 4; ++r)
        E[(tb + r)*264 + cl] = f2bf(acc[m][n][r] * invs[tb + r]);
    }
  __syncthreads();
  #pragma unroll
  for (int i = 0; i < 4; ++i) {
    int s = tid + 512*i;                  // 2048 16B-chunks
    int tl = s >> 5, c8 = (s & 31)*8;
    ulonglong2 v = *(const ulonglong2*)(&E[tl*264 + c8]);
    *(ulonglong2*)(aoH + ((size_t)h*TT + t0 + tl)*768 + c0 + c8) = v;   // full-line writes
  }
}

// ---------------- K3: out-proj as 16 plane-GEMMs over head-major aoH ----------------
// grid (16 t-tiles(64), 16 j, nb); K = 8 head-chunks x 96 ([ao_j(h) | ao_srcj(h)])
__global__ __launch_bounds__(256) void k3_mfma(const ushort* __restrict__ aoH0,
                                               const ushort* __restrict__ wBt,
                                               const float* __restrict__ b_next,
                                               const float* __restrict__ hidden,
                                               float* __restrict__ out, int b0) {
  const int lb = blockIdx.z;
  const ushort* aoH = aoH0 + (size_t)lb*AO_S;
  const float* hidden_b = hidden + (size_t)(b0 + lb)*TT*768;
  float* out_b = out + (size_t)(b0 + lb)*TT*768;
  const int j = blockIdx.y, t0 = blockIdx.x*64;
  const int srcj = c_srcj[j];
  __shared__ __align__(16) ushort As[64*104];
  __shared__ __align__(16) ushort Bs[48*104];
  const int tid = threadIdx.x;
  const int lane = tid & 63, wid = tid >> 6;
  const int rr = lane & 15, kq = lane >> 4;
  const ushort* bw = wBt + (size_t)j*48*768;
  const int ar = tid >> 2, aq = tid & 3;       // stage: 4 thr/row, 3 chunks each
  f32x4 acc[3] = {};
  for (int hh = 0; hh < HH; ++hh) {
    __syncthreads();
    {
      const ushort* rowp = aoH + ((size_t)hh*TT + t0 + ar)*768;
      #pragma unroll
      for (int q = 0; q < 3; ++q) {
        int ci = aq*3 + q;                     // 0..11
        const ushort* src = rowp + ((ci < 6) ? (j*48 + ci*8) : (srcj*48 + (ci - 6)*8));
        *(ulonglong2*)(&As[ar*104 + ci*8]) = *(const ulonglong2*)src;
      }
      if (tid < 192) {
        const ushort* brow = bw + (size_t)ar*768 + hh*96;
        #pragma unroll
        for (int q = 0; q < 3; ++q) {
          int ci = aq*3 + q;
          *(ulonglong2*)(&Bs[ar*104 + ci*8]) = *(const ulonglong2*)(brow + ci*8);
        }
      }
    }
    __syncthreads();
    #pragma unroll
    for (int ks = 0; ks < 3; ++ks) {
      bf16x8 af = *(const bf16x8*)(&As[(wid*16 + rr)*104 + ks*32 + kq*8]);
      #pragma unroll
      for (int n = 0; n < 3; ++n) {
        bf16x8 bf = *(const bf16x8*)(&Bs[(n*16 + rr)*104 + ks*32 + kq*8]);
        acc[n] = __builtin_amdgcn_mfma_f32_16x16x32_bf16(af, bf, acc[n], 0, 0, 0);
      }
    }
  }
  const int cr = (lane >> 4) << 2, cc = lane & 15;
  #pragma unroll
  for (int n = 0; n < 3; ++n) {
    int o = n*16 + cc;
    float bb = (j == 0) ? b_next[o] : 0.f;
    #pragma unroll
    for (int r = 0; r < 4; ++r) {
      int t = t0 + wid*16 + cr + r;
      size_t off = (size_t)t*768 + o*16 + j;
      out_b[off] = acc[n][r] + bb + hidden_b[off];
    }
  }
}

extern "C" void kernel_launch(void* const* d_in, const int* in_sizes, int n_in,
                              void* d_out, int out_size, void* d_ws, size_t ws_size,
                              hipStream_t stream) {
  const float* hidden = (const float*)d_in[0];
  const float* w_attn = (const float*)d_in[1];
  const float* b_attn = (const float*)d_in[2];
  const float* w_next = (const float*)d_in[3];
  const float* b_next = (const float*)d_in[4];
  const float* ln_w   = (const float*)d_in[5];
  float* out = (float*)d_out;
  float* ws = (float*)d_ws;

  const size_t W_FL = (16*48*768 + 16*1152*96)/2;   // wBt + wB in floats = 589,824
  int nb = 0;
  for (int g = 4; g >= 1; g >>= 1) {
    size_t need = ((size_t)g*(U_S/2 + RP_S + QF_S /*qf+kf in fl*/ + VT_S/2 + AO_S/2 + HTB_S/2) + W_FL)*4;
    if (ws_size >= need) { nb = g; break; }
  }
  if (nb == 0) {
    kfill<<<2048, 256, 0, stream>>>(out, (size_t)out_size, 1.0e6f);
    return;
  }

  // layout (ushort* unless noted); strides per batch
  ushort* ubuf    = (ushort*)ws;                                  // nb * U_S
  float*  rowpart = ws + (size_t)nb*(U_S/2);                      // nb * RP_S f32
  ushort* qf      = (ushort*)(rowpart + (size_t)nb*RP_S);         // nb * QF_S
  ushort* kf      = qf + (size_t)nb*QF_S;                         // nb * QF_S
  ushort* vT      = kf + (size_t)nb*QF_S;                         // nb * VT_S
  ushort* aoH     = vT + (size_t)nb*VT_S;                         // nb * AO_S
  ushort* hTb     = aoH + (size_t)nb*AO_S;                        // nb * HTB_S
  ushort* wBt     = hTb + (size_t)nb*HTB_S;                       // 16*48*768
  ushort* wB      = wBt + (size_t)16*48*768;                      // 16*1152*96

  k0b_wplanes<<<1152, 256, 0, stream>>>(w_next, wBt);
  k0c_wqkv<<<3456, 256, 0, stream>>>(w_attn, wB);
  for (int b0 = 0; b0 < BB; b0 += nb) {
    k1_rmsnorm<<<dim3(TT, nb), 256, 0, stream>>>(hidden, ln_w, hTb, b0);
    k1b_qkv_mfma<<<dim3(8, 9, 16*nb), 256, 0, stream>>>(hTb, wB, b_attn, qf, kf, vT);
    k1c_extras<<<dim3(THD_B/4, nb), 256, 0, stream>>>(qf, kf);
    k2b_logits_mfma<<<dim3(8, 16, 8*nb), 256, 0, stream>>>(qf, kf, ubuf, rowpart);
    k2d_pv_mfma<<<nb*8*16*3, 512, 0, stream>>>(ubuf, vT, rowpart, aoH);
    k3_mfma<<<dim3(16, 16, nb), 256, 0, stream>>>(aoH, wBt, b_next, hidden, out, b0);
  }
}